// Round 3
// baseline (45664.536 us; speedup 1.0000x reference)
//
#include <hip/hip_runtime.h>
#include <hip/hip_cooperative_groups.h>

namespace cg = cooperative_groups;

// LSTMGapFiller R4: decoder -> single persistent cooperative kernel.
// Per step: phase A (gen l0, inline argmax of prev logits) | grid.sync |
// phase B (gen l1 + shuffle-reduced partial logits atomicAdd into bias-
// prefilled out) | grid.sync. c-state in registers; 12 independent MFMA
// accumulator chains (aHH/aLH/aHL x 4 gates). Context stack unchanged (R3).

#define L_SEQ 100
#define BATCH 1024
#define HCTX 256
#define HG 512
#define TDEC 256

typedef __attribute__((ext_vector_type(8))) short bf16x8;
typedef __attribute__((ext_vector_type(4))) float f32x4;

__device__ __forceinline__ float sigf(float x){ return 1.0f/(1.0f+expf(-x)); }
__device__ __forceinline__ unsigned short f2bf(float x){
  unsigned int u = __float_as_uint(x);
  return (unsigned short)((u + 0x7fffu + ((u>>16)&1u)) >> 16);   // RNE
}
__device__ __forceinline__ float bf2f(unsigned short h){
  return __uint_as_float(((unsigned int)h)<<16);
}

// Pack W[G][K] (fp32, row-major) into MFMA-fragment-linear bf16 hi/lo.
__global__ void pack_w(const float* __restrict__ W, int G, int K, int KTtot, int kt0,
                       unsigned short* __restrict__ hi, unsigned short* __restrict__ lo){
  int idx = blockIdx.x*blockDim.x + threadIdx.x;
  int kt_n = K/32;
  int total = (G/16)*kt_n*64;
  if (idx >= total) return;
  int lane = idx & 63;
  int ktl = (idx>>6) % kt_n;
  int gt  = (idx>>6) / kt_n;
  int g = gt*16 + (lane & 15);
  int k = ktl*32 + (lane>>4)*8;
  const float* src = W + (size_t)g*K + k;
  size_t dst = (((size_t)gt*KTtot + (kt0 + ktl))*64 + lane)*8;
  #pragma unroll
  for (int j=0;j<8;j++){
    float x = src[j];
    unsigned short h = f2bf(x);
    hi[dst+j] = h;
    lo[dst+j] = f2bf(x - bf2f(h));
  }
}

// embedding projections (vocab=5)
__global__ void embprep(const float* __restrict__ emb,
                        const float* __restrict__ c0Wih, const float* __restrict__ c0b,
                        const float* __restrict__ g0Wih, const float* __restrict__ g0b,
                        float* __restrict__ ectx0, float* __restrict__ egen0){
  int idx = blockIdx.x*blockDim.x + threadIdx.x;
  if (idx < 2*5*1024){
    int d = idx / 5120;
    int v = (idx / 1024) % 5;
    int j = idx % 1024;
    const float* w = c0Wih + ((size_t)d*1024 + j)*64;
    const float* e = emb + v*64;
    float s = c0b[d*1024 + j];
    #pragma unroll
    for (int k=0;k<64;k++) s += e[k]*w[k];
    ectx0[idx] = s;
  } else if (idx < 2*5*1024 + 5*2048){
    int i2 = idx - 10240;
    int v = i2 / 2048;
    int j = i2 % 2048;
    const float* w = g0Wih + (size_t)j*64;
    const float* e = emb + v*64;
    float s = g0b[j];
    #pragma unroll
    for (int k=0;k<64;k++) s += e[k]*w[k];
    egen0[i2] = s;
  }
}

// prefill output logits with bias (atomic partials add onto this)
__global__ void prefill_out(float* __restrict__ out, const float* __restrict__ outb){
  int i = blockIdx.x*blockDim.x + threadIdx.x;
  if (i < BATCH*TDEC*5) out[i] = outb[i%5];
}

// ---------------- context layer 0 (MFMA) ---------------- (unchanged R3)
__global__ void __launch_bounds__(512,1) ctx_l0_mfma(
    const int* __restrict__ toks,
    const float* __restrict__ ectx0,
    const unsigned short* __restrict__ wh, const unsigned short* __restrict__ wl,
    unsigned short* __restrict__ y0h, unsigned short* __restrict__ y0l)
{
  const int id  = blockIdx.x;
  const int dir = (id >> 2) & 1;
  const int bx  = ((id >> 3) << 2) | (id & 3);
  const int e0  = bx * 16;
  const int lane = threadIdx.x & 63;
  const int w    = threadIdx.x >> 6;
  const int lo16 = lane & 15, kgrp = lane >> 4;

  __shared__ unsigned short hsh[16*256];
  __shared__ unsigned short hsl[16*256];
  __shared__ float cs[16*256];
  for (int i=threadIdx.x;i<16*256;i+=512){ hsh[i]=0; hsl[i]=0; cs[i]=0.f; }
  __syncthreads();

  const unsigned short* pbh[4][2];
  const unsigned short* pbl[4][2];
  #pragma unroll
  for (int g=0;g<4;g++){
    #pragma unroll
    for (int st=0;st<2;st++){
      int ct = g*16 + w*2 + st;
      size_t off = (size_t)dir*1024*256 + ((size_t)(ct*8)*64 + lane)*8;
      pbh[g][st] = wh + off; pbl[g][st] = wl + off;
    }
  }
  const unsigned aoff0 = (unsigned)(lo16*512 + kgrp*16);
  const unsigned axor  = ((unsigned)(lo16 & 7)) << 4;

  for (int s=0;s<L_SEQ;s++){
    const int t = dir ? (L_SEQ-1-s) : s;
    f32x4 zero = {0.f,0.f,0.f,0.f};
    f32x4 acc[4][2];
    #pragma unroll
    for (int g=0;g<4;g++){
      #pragma unroll
      for (int st=0;st<2;st++) acc[g][st] = zero;
    }
    #pragma unroll 2
    for (int kt=0;kt<8;kt++){
      unsigned ao = (aoff0 + kt*64) ^ axor;
      bf16x8 ah = *(const bf16x8*)((const char*)hsh + ao);
      bf16x8 al = *(const bf16x8*)((const char*)hsl + ao);
      #pragma unroll
      for (int g=0;g<4;g++){
        #pragma unroll
        for (int st=0;st<2;st++){
          bf16x8 bh = *(const bf16x8*)(pbh[g][st] + (size_t)kt*512);
          bf16x8 bl = *(const bf16x8*)(pbl[g][st] + (size_t)kt*512);
          acc[g][st] = __builtin_amdgcn_mfma_f32_16x16x32_bf16(ah,bh,acc[g][st],0,0,0);
          acc[g][st] = __builtin_amdgcn_mfma_f32_16x16x32_bf16(al,bh,acc[g][st],0,0,0);
          acc[g][st] = __builtin_amdgcn_mfma_f32_16x16x32_bf16(ah,bl,acc[g][st],0,0,0);
        }
      }
    }
    __syncthreads();
    int tkr[4];
    #pragma unroll
    for (int r=0;r<4;r++) tkr[r] = toks[(e0 + kgrp*4 + r)*L_SEQ + t];
    #pragma unroll
    for (int st=0;st<2;st++){
      const int unit = w*32 + st*16 + lo16;
      #pragma unroll
      for (int r=0;r<4;r++){
        const int row = kgrp*4 + r;
        const int e = e0 + row;
        const float* ep = ectx0 + ((size_t)(dir*5 + tkr[r]))*1024 + unit;
        float zi = acc[0][st][r] + ep[0];
        float zf = acc[1][st][r] + ep[256];
        float zg = acc[2][st][r] + ep[512];
        float zo = acc[3][st][r] + ep[768];
        int ci = row*256 + unit;
        float c = sigf(zf)*cs[ci] + sigf(zi)*tanhf(zg);
        float h = sigf(zo)*tanhf(c);
        cs[ci] = c;
        unsigned short hb = f2bf(h), lb = f2bf(h - bf2f(hb));
        unsigned hoff = ((unsigned)(row*512 + unit*2)) ^ (((unsigned)(row & 7)) << 4);
        *(unsigned short*)((char*)hsh + hoff) = hb;
        *(unsigned short*)((char*)hsl + hoff) = lb;
        size_t yo = ((size_t)t*BATCH + e)*512 + dir*256 + unit;
        y0h[yo] = hb; y0l[yo] = lb;
      }
    }
    __syncthreads();
  }
}

// ---------------- context layer 1 (MFMA) ---------------- (unchanged R3)
__global__ void __launch_bounds__(512,1) ctx_l1_mfma(
    const unsigned short* __restrict__ y0h, const unsigned short* __restrict__ y0l,
    const unsigned short* __restrict__ wh, const unsigned short* __restrict__ wl,
    const float* __restrict__ bias,
    float* __restrict__ finals, int t_store)
{
  const int id  = blockIdx.x;
  const int dir = (id >> 2) & 1;
  const int bx  = ((id >> 3) << 2) | (id & 3);
  const int e0  = bx * 16;
  const int lane = threadIdx.x & 63;
  const int w    = threadIdx.x >> 6;
  const int lo16 = lane & 15, kgrp = lane >> 4;

  __shared__ unsigned short xsh[16*512];
  __shared__ unsigned short xsl[16*512];
  __shared__ unsigned short hsh[16*256];
  __shared__ unsigned short hsl[16*256];
  __shared__ float cs[16*256];
  for (int i=threadIdx.x;i<16*256;i+=512){ hsh[i]=0; hsl[i]=0; cs[i]=0.f; }

  float bb[4][2];
  #pragma unroll
  for (int g=0;g<4;g++){
    #pragma unroll
    for (int st=0;st<2;st++)
      bb[g][st] = bias[dir*1024 + g*256 + w*32 + st*16 + lo16];
  }
  const unsigned short* pbh[4][2];
  const unsigned short* pbl[4][2];
  #pragma unroll
  for (int g=0;g<4;g++){
    #pragma unroll
    for (int st=0;st<2;st++){
      int ct = g*16 + w*2 + st;
      size_t off = (size_t)dir*1024*768 + ((size_t)(ct*24)*64 + lane)*8;
      pbh[g][st] = wh + off; pbl[g][st] = wl + off;
    }
  }
  const unsigned axor = ((unsigned)(lo16 & 7)) << 4;
  __syncthreads();

  for (int s=0;s<L_SEQ;s++){
    const int t = dir ? (L_SEQ-1-s) : s;
    #pragma unroll
    for (int cc=0; cc<2; cc++){
      int ci = threadIdx.x + cc*512;
      int row = ci >> 6, cr = ci & 63;
      const unsigned short* srcbase = y0h + ((size_t)t*BATCH + e0 + row)*512 + cr*8;
      const unsigned short* srcbasel = y0l + ((size_t)t*BATCH + e0 + row)*512 + cr*8;
      uint4 vh = *(const uint4*)srcbase;
      uint4 vl = *(const uint4*)srcbasel;
      unsigned xo = ((unsigned)(row*1024 + cr*16)) ^ (((unsigned)(row & 7)) << 4);
      *(uint4*)((char*)xsh + xo) = vh;
      *(uint4*)((char*)xsl + xo) = vl;
    }
    __syncthreads();
    f32x4 zero = {0.f,0.f,0.f,0.f};
    f32x4 acc[4][2];
    #pragma unroll
    for (int g=0;g<4;g++){
      #pragma unroll
      for (int st=0;st<2;st++) acc[g][st] = zero;
    }
    #pragma unroll 2
    for (int kt=0;kt<16;kt++){
      unsigned ao = ((unsigned)(lo16*1024 + kt*64 + kgrp*16)) ^ axor;
      bf16x8 ah = *(const bf16x8*)((const char*)xsh + ao);
      bf16x8 al = *(const bf16x8*)((const char*)xsl + ao);
      #pragma unroll
      for (int g=0;g<4;g++){
        #pragma unroll
        for (int st=0;st<2;st++){
          bf16x8 bh = *(const bf16x8*)(pbh[g][st] + (size_t)kt*512);
          bf16x8 bl = *(const bf16x8*)(pbl[g][st] + (size_t)kt*512);
          acc[g][st] = __builtin_amdgcn_mfma_f32_16x16x32_bf16(ah,bh,acc[g][st],0,0,0);
          acc[g][st] = __builtin_amdgcn_mfma_f32_16x16x32_bf16(al,bh,acc[g][st],0,0,0);
          acc[g][st] = __builtin_amdgcn_mfma_f32_16x16x32_bf16(ah,bl,acc[g][st],0,0,0);
        }
      }
    }
    #pragma unroll 2
    for (int kt=16;kt<24;kt++){
      unsigned ao = ((unsigned)(lo16*512 + (kt-16)*64 + kgrp*16)) ^ axor;
      bf16x8 ah = *(const bf16x8*)((const char*)hsh + ao);
      bf16x8 al = *(const bf16x8*)((const char*)hsl + ao);
      #pragma unroll
      for (int g=0;g<4;g++){
        #pragma unroll
        for (int st=0;st<2;st++){
          bf16x8 bh = *(const bf16x8*)(pbh[g][st] + (size_t)kt*512);
          bf16x8 bl = *(const bf16x8*)(pbl[g][st] + (size_t)kt*512);
          acc[g][st] = __builtin_amdgcn_mfma_f32_16x16x32_bf16(ah,bh,acc[g][st],0,0,0);
          acc[g][st] = __builtin_amdgcn_mfma_f32_16x16x32_bf16(al,bh,acc[g][st],0,0,0);
          acc[g][st] = __builtin_amdgcn_mfma_f32_16x16x32_bf16(ah,bl,acc[g][st],0,0,0);
        }
      }
    }
    __syncthreads();
    #pragma unroll
    for (int st=0;st<2;st++){
      const int unit = w*32 + st*16 + lo16;
      #pragma unroll
      for (int r=0;r<4;r++){
        const int row = kgrp*4 + r;
        float zi = acc[0][st][r] + bb[0][st];
        float zf = acc[1][st][r] + bb[1][st];
        float zg = acc[2][st][r] + bb[2][st];
        float zo = acc[3][st][r] + bb[3][st];
        int ci = row*256 + unit;
        float c = sigf(zf)*cs[ci] + sigf(zi)*tanhf(zg);
        float h = sigf(zo)*tanhf(c);
        cs[ci] = c;
        unsigned short hb = f2bf(h), lb = f2bf(h - bf2f(hb));
        unsigned hoff = ((unsigned)(row*512 + unit*2)) ^ (((unsigned)(row & 7)) << 4);
        *(unsigned short*)((char*)hsh + hoff) = hb;
        *(unsigned short*)((char*)hsl + hoff) = lb;
        if (t == t_store)
          finals[(size_t)(e0 + row)*512 + dir*256 + unit] = h;
      }
    }
    __syncthreads();
  }
}

__global__ void combine_init2(const float* __restrict__ lf, const float* __restrict__ rf,
                              unsigned short* __restrict__ h0h, unsigned short* __restrict__ h0l,
                              unsigned short* __restrict__ h1h, unsigned short* __restrict__ h1l){
  int i = blockIdx.x*blockDim.x + threadIdx.x;
  if (i < BATCH*HG){
    float v = 0.5f*(lf[i]+rf[i]);
    unsigned short h = f2bf(v);
    unsigned short l = f2bf(v - bf2f(h));
    h0h[i]=h; h0l[i]=l; h1h[i]=h; h1l[i]=l;
  }
}

// ---------------- persistent decoder (cooperative) ----------------
// 256 blocks x 512 thr, 1 block/CU. Per step:
//   A: h0 = lstm(egen0[tok], h0)   [tok argmax'd inline from out[t-1]]
//   sync
//   B: h1 = lstm(h0, h1); partial logits -> atomicAdd into pre-biased out
//   sync
// c-state lives in registers (same thread owns same (row,unit) all steps).
__global__ void __launch_bounds__(512,2) dec_persist(
    const float* __restrict__ egen0,
    const unsigned short* __restrict__ w0h, const unsigned short* __restrict__ w0l,
    const unsigned short* __restrict__ w1h, const unsigned short* __restrict__ w1l,
    const float* __restrict__ bias1,
    const float* __restrict__ outW,
    unsigned short* __restrict__ h0ha, unsigned short* __restrict__ h0la,
    unsigned short* __restrict__ h0hb, unsigned short* __restrict__ h0lb,
    unsigned short* __restrict__ h1ha, unsigned short* __restrict__ h1la,
    unsigned short* __restrict__ h1hb, unsigned short* __restrict__ h1lb,
    float* __restrict__ out)
{
  cg::grid_group grid = cg::this_grid();
  const int bid = blockIdx.x;
  const int by = bid & 15;            // unit-group (32 units) -> XCD-local weights
  const int bx = bid >> 4;            // elem-group (64 rows)
  const int e0 = bx * 64;
  const int lane = threadIdx.x & 63;
  const int w = threadIdx.x >> 6;
  const int wm = w & 3;
  const int wu = w >> 2;
  const int ut = by*2 + wu;
  const int lo16 = lane & 15;
  const int kgrp = lane >> 4;
  const int arow = e0 + wm*16 + lo16;   // A-fragment row
  const int u = ut*16 + lo16;           // owned unit
  const int r0 = e0 + wm*16 + kgrp*4;   // D rows r0..r0+3

  const float b10 = bias1[u], b11 = bias1[512+u];
  const float b12 = bias1[1024+u], b13 = bias1[1536+u];
  float ow[5];
  #pragma unroll
  for (int v=0;v<5;v++) ow[v] = outW[v*512 + u];

  const unsigned short* p0[8];
  const unsigned short* p1[8];
  #pragma unroll
  for (int q=0;q<4;q++){
    size_t o0 = ((size_t)(q*32+ut)*16*64 + lane)*8;   // KT=16
    p0[q] = w0h + o0; p0[q+4] = w0l + o0;
    size_t o1 = ((size_t)(q*32+ut)*32*64 + lane)*8;   // KT=32
    p1[q] = w1h + o1; p1[q+4] = w1l + o1;
  }
  float c0r[4] = {0.f,0.f,0.f,0.f};
  float c1r[4] = {0.f,0.f,0.f,0.f};
  const f32x4 z4 = {0.f,0.f,0.f,0.f};

  for (int t=0;t<TDEC;t++){
    const unsigned short* h0ih = (t&1)? h0hb : h0ha;
    const unsigned short* h0il = (t&1)? h0lb : h0la;
    unsigned short* h0oh = (t&1)? h0ha : h0hb;
    unsigned short* h0ol = (t&1)? h0la : h0lb;
    const unsigned short* h1ih = (t&1)? h1hb : h1ha;
    const unsigned short* h1il = (t&1)? h1lb : h1la;
    unsigned short* h1oh = (t&1)? h1ha : h1hb;
    unsigned short* h1ol = (t&1)? h1la : h1lb;

    // -------- phase A: generator layer 0 --------
    {
      const unsigned short* pah = h0ih + (size_t)arow*512 + kgrp*8;
      const unsigned short* pal = h0il + (size_t)arow*512 + kgrp*8;
      f32x4 aHH[4]={z4,z4,z4,z4}, aLH[4]={z4,z4,z4,z4}, aHL[4]={z4,z4,z4,z4};
      #pragma unroll 2
      for (int ks=0;ks<16;ks++){
        bf16x8 ah = *(const bf16x8*)(pah + ks*32);
        bf16x8 al = *(const bf16x8*)(pal + ks*32);
        #pragma unroll
        for (int q=0;q<4;q++){
          bf16x8 bh = *(const bf16x8*)(p0[q]   + (size_t)ks*512);
          bf16x8 bl = *(const bf16x8*)(p0[q+4] + (size_t)ks*512);
          aHH[q] = __builtin_amdgcn_mfma_f32_16x16x32_bf16(ah,bh,aHH[q],0,0,0);
          aLH[q] = __builtin_amdgcn_mfma_f32_16x16x32_bf16(al,bh,aLH[q],0,0,0);
          aHL[q] = __builtin_amdgcn_mfma_f32_16x16x32_bf16(ah,bl,aHL[q],0,0,0);
        }
      }
      int tkr[4];
      #pragma unroll
      for (int r=0;r<4;r++){
        int tk = 0;
        if (t > 0){
          const float* lp = out + ((size_t)(r0+r)*TDEC + (t-1))*5;
          float l0=lp[0],l1=lp[1],l2=lp[2],l3=lp[3],l4=lp[4];
          float best=l0;
          if (l1>best){best=l1;tk=1;}
          if (l2>best){best=l2;tk=2;}
          if (l3>best){best=l3;tk=3;}
          if (l4>best){best=l4;tk=4;}
        }
        tkr[r]=tk;
      }
      #pragma unroll
      for (int r=0;r<4;r++){
        const int e = r0 + r;
        const float* ep = egen0 + (size_t)tkr[r]*2048 + u;
        float zi = aHH[0][r]+aLH[0][r]+aHL[0][r] + ep[0];
        float zf = aHH[1][r]+aLH[1][r]+aHL[1][r] + ep[512];
        float zg = aHH[2][r]+aLH[2][r]+aHL[2][r] + ep[1024];
        float zo = aHH[3][r]+aLH[3][r]+aHL[3][r] + ep[1536];
        float c = sigf(zf)*c0r[r] + sigf(zi)*tanhf(zg);
        float h = sigf(zo)*tanhf(c);
        c0r[r] = c;
        const size_t idx = (size_t)e*512 + u;
        unsigned short hb = f2bf(h);
        h0oh[idx] = hb;
        h0ol[idx] = f2bf(h - bf2f(hb));
      }
    }
    grid.sync();

    // -------- phase B: generator layer 1 + logit partials --------
    {
      const unsigned short* pxh = h0oh + (size_t)arow*512 + kgrp*8;
      const unsigned short* pxl = h0ol + (size_t)arow*512 + kgrp*8;
      const unsigned short* pah = h1ih + (size_t)arow*512 + kgrp*8;
      const unsigned short* pal = h1il + (size_t)arow*512 + kgrp*8;
      f32x4 aHH[4]={z4,z4,z4,z4}, aLH[4]={z4,z4,z4,z4}, aHL[4]={z4,z4,z4,z4};
      #pragma unroll 2
      for (int ks=0;ks<16;ks++){          // k 0..511 : x = h0out
        bf16x8 ah = *(const bf16x8*)(pxh + ks*32);
        bf16x8 al = *(const bf16x8*)(pxl + ks*32);
        #pragma unroll
        for (int q=0;q<4;q++){
          bf16x8 bh = *(const bf16x8*)(p1[q]   + (size_t)ks*512);
          bf16x8 bl = *(const bf16x8*)(p1[q+4] + (size_t)ks*512);
          aHH[q] = __builtin_amdgcn_mfma_f32_16x16x32_bf16(ah,bh,aHH[q],0,0,0);
          aLH[q] = __builtin_amdgcn_mfma_f32_16x16x32_bf16(al,bh,aLH[q],0,0,0);
          aHL[q] = __builtin_amdgcn_mfma_f32_16x16x32_bf16(ah,bl,aHL[q],0,0,0);
        }
      }
      #pragma unroll 2
      for (int ks=16;ks<32;ks++){         // k 512..1023 : h1 prev
        bf16x8 ah = *(const bf16x8*)(pah + (ks-16)*32);
        bf16x8 al = *(const bf16x8*)(pal + (ks-16)*32);
        #pragma unroll
        for (int q=0;q<4;q++){
          bf16x8 bh = *(const bf16x8*)(p1[q]   + (size_t)ks*512);
          bf16x8 bl = *(const bf16x8*)(p1[q+4] + (size_t)ks*512);
          aHH[q] = __builtin_amdgcn_mfma_f32_16x16x32_bf16(ah,bh,aHH[q],0,0,0);
          aLH[q] = __builtin_amdgcn_mfma_f32_16x16x32_bf16(al,bh,aLH[q],0,0,0);
          aHL[q] = __builtin_amdgcn_mfma_f32_16x16x32_bf16(ah,bl,aHL[q],0,0,0);
        }
      }
      float hv[4];
      #pragma unroll
      for (int r=0;r<4;r++){
        const int e = r0 + r;
        float zi = aHH[0][r]+aLH[0][r]+aHL[0][r] + b10;
        float zf = aHH[1][r]+aLH[1][r]+aHL[1][r] + b11;
        float zg = aHH[2][r]+aLH[2][r]+aHL[2][r] + b12;
        float zo = aHH[3][r]+aLH[3][r]+aHL[3][r] + b13;
        float c = sigf(zf)*c1r[r] + sigf(zi)*tanhf(zg);
        float h = sigf(zo)*tanhf(c);
        c1r[r] = c;
        hv[r] = h;
        const size_t idx = (size_t)e*512 + u;
        unsigned short hb = f2bf(h);
        h1oh[idx] = hb;
        h1ol[idx] = f2bf(h - bf2f(hb));
      }
      // partial logits: reduce over the 16 lanes (units u..u+15 of this tile)
      #pragma unroll
      for (int r=0;r<4;r++){
        #pragma unroll
        for (int v=0;v<5;v++){
          float psum = hv[r]*ow[v];
          psum += __shfl_xor(psum, 1);
          psum += __shfl_xor(psum, 2);
          psum += __shfl_xor(psum, 4);
          psum += __shfl_xor(psum, 8);
          if (lo16 == 0)
            atomicAdd(out + ((size_t)(r0+r)*TDEC + t)*5 + v, psum);
        }
      }
    }
    grid.sync();
  }
}

extern "C" void kernel_launch(void* const* d_in, const int* in_sizes, int n_in,
                              void* d_out, int out_size, void* d_ws, size_t ws_size,
                              hipStream_t stream){
  (void)in_sizes; (void)n_in; (void)out_size;
  const int*   leftc    = (const int*)d_in[0];
  const int*   rightc   = (const int*)d_in[1];
  const float* emb      = (const float*)d_in[3];
  const float* ctx0_Wih = (const float*)d_in[4];
  const float* ctx0_Whh = (const float*)d_in[5];
  const float* ctx0_b   = (const float*)d_in[6];
  const float* ctx1_Wih = (const float*)d_in[7];
  const float* ctx1_Whh = (const float*)d_in[8];
  const float* ctx1_b   = (const float*)d_in[9];
  const float* gen0_Wih = (const float*)d_in[10];
  const float* gen0_Whh = (const float*)d_in[11];
  const float* gen0_b   = (const float*)d_in[12];
  const float* gen1_Wih = (const float*)d_in[13];
  const float* gen1_Whh = (const float*)d_in[14];
  const float* gen1_b   = (const float*)d_in[15];
  const float* out_W    = (const float*)d_in[16];
  const float* out_b    = (const float*)d_in[17];
  float* out = (float*)d_out;

  char* p = (char*)d_ws;
  auto carve = [&](size_t nfloats)->float*{
    float* r = (float*)p;
    p += ((nfloats*sizeof(float) + 255) & ~(size_t)255);
    return r;
  };
  auto carveu = [&](size_t nush)->unsigned short*{
    return (unsigned short*)carve((nush + 1)/2);
  };
  float* ectx0  = carve(2*5*1024);
  float* egen0  = carve(5*2048);
  float* leftF  = carve((size_t)BATCH*HG);
  float* rightF = carve((size_t)BATCH*HG);
  unsigned short* c0pkh = carveu((size_t)2*1024*256);
  unsigned short* c0pkl = carveu((size_t)2*1024*256);
  unsigned short* c1pkh = carveu((size_t)2*1024*768);
  unsigned short* c1pkl = carveu((size_t)2*1024*768);
  unsigned short* pk0h = carveu((size_t)2048*512);
  unsigned short* pk0l = carveu((size_t)2048*512);
  unsigned short* pk1h = carveu((size_t)2048*1024);
  unsigned short* pk1l = carveu((size_t)2048*1024);
  unsigned short* h0ha = carveu((size_t)BATCH*HG);
  unsigned short* h0la = carveu((size_t)BATCH*HG);
  unsigned short* h0hb = carveu((size_t)BATCH*HG);
  unsigned short* h0lb = carveu((size_t)BATCH*HG);
  unsigned short* h1ha = carveu((size_t)BATCH*HG);
  unsigned short* h1la = carveu((size_t)BATCH*HG);
  unsigned short* h1hb = carveu((size_t)BATCH*HG);
  unsigned short* h1lb = carveu((size_t)BATCH*HG);
  unsigned short* y0h = carveu((size_t)L_SEQ*BATCH*512);   // 105 MB
  unsigned short* y0l = carveu((size_t)L_SEQ*BATCH*512);   // 105 MB
  if ((size_t)(p - (char*)d_ws) > ws_size) return;  // insufficient workspace -> loud fail

  // weight packs (fragment-linear bf16 hi/lo)
  for (int d=0; d<2; d++){
    pack_w<<<128, 256, 0, stream>>>(ctx0_Whh + (size_t)d*1024*256, 1024, 256, 8, 0,
                                    c0pkh + (size_t)d*262144, c0pkl + (size_t)d*262144);
    pack_w<<<256, 256, 0, stream>>>(ctx1_Wih + (size_t)d*1024*512, 1024, 512, 24, 0,
                                    c1pkh + (size_t)d*786432, c1pkl + (size_t)d*786432);
    pack_w<<<128, 256, 0, stream>>>(ctx1_Whh + (size_t)d*1024*256, 1024, 256, 24, 16,
                                    c1pkh + (size_t)d*786432, c1pkl + (size_t)d*786432);
  }
  pack_w<<<512, 256, 0, stream>>>(gen0_Whh, 2048, 512, 16,  0, pk0h, pk0l);
  pack_w<<<512, 256, 0, stream>>>(gen1_Wih, 2048, 512, 32,  0, pk1h, pk1l);
  pack_w<<<512, 256, 0, stream>>>(gen1_Whh, 2048, 512, 32, 16, pk1h, pk1l);

  embprep<<<(20480+255)/256, 256, 0, stream>>>(emb, ctx0_Wih, ctx0_b,
                                               gen0_Wih, gen0_b, ectx0, egen0);
  prefill_out<<<(BATCH*TDEC*5+255)/256, 256, 0, stream>>>(out, out_b);

  // left encode (finals at t=99), then right (finals at t=0); y0 reused
  ctx_l0_mfma<<<128, 512, 0, stream>>>(leftc, ectx0, c0pkh, c0pkl, y0h, y0l);
  ctx_l1_mfma<<<128, 512, 0, stream>>>(y0h, y0l, c1pkh, c1pkl, ctx1_b, leftF, L_SEQ-1);
  ctx_l0_mfma<<<128, 512, 0, stream>>>(rightc, ectx0, c0pkh, c0pkl, y0h, y0l);
  ctx_l1_mfma<<<128, 512, 0, stream>>>(y0h, y0l, c1pkh, c1pkl, ctx1_b, rightF, 0);

  combine_init2<<<(BATCH*HG+255)/256, 256, 0, stream>>>(leftF, rightF,
                                                        h0ha, h0la, h1ha, h1la);

  void* kargs[] = {
    (void*)&egen0, (void*)&pk0h, (void*)&pk0l, (void*)&pk1h, (void*)&pk1l,
    (void*)&gen1_b, (void*)&out_W,
    (void*)&h0ha, (void*)&h0la, (void*)&h0hb, (void*)&h0lb,
    (void*)&h1ha, (void*)&h1la, (void*)&h1hb, (void*)&h1lb,
    (void*)&out
  };
  hipLaunchCooperativeKernel((void*)dec_persist, dim3(256), dim3(512),
                             kargs, 0, stream);
}

// Round 4
// 34188.486 us; speedup vs baseline: 1.3357x; 1.3357x over previous
//
#include <hip/hip_runtime.h>

// LSTMGapFiller R5: drop persistent/grid.sync (measured: 74us/sync, L2-inv
// refetch at 230 GB/s = 148us/step). Back to per-step launches but 2/step:
// dec_l0 (inline argmax of out[t-1]) + dec_l1out (logits fused via shfl+
// atomicAdd into bias-prefilled out). Both dec kernels get explicit depth-2
// load pipelines (20 outstanding dwordx4/wave) to raise the unavoidable
// post-invalidate weight refetch from ~230 GB/s latency-bound to BW-bound.
// Context stack unchanged (R3, MFMA + LDS-resident state).

#define L_SEQ 100
#define BATCH 1024
#define HCTX 256
#define HG 512
#define TDEC 256

typedef __attribute__((ext_vector_type(8))) short bf16x8;
typedef __attribute__((ext_vector_type(4))) float f32x4;

__device__ __forceinline__ float sigf(float x){ return 1.0f/(1.0f+expf(-x)); }
__device__ __forceinline__ unsigned short f2bf(float x){
  unsigned int u = __float_as_uint(x);
  return (unsigned short)((u + 0x7fffu + ((u>>16)&1u)) >> 16);   // RNE
}
__device__ __forceinline__ float bf2f(unsigned short h){
  return __uint_as_float(((unsigned int)h)<<16);
}

// fragment set: A(hi,lo) + 4 gate col-tiles B(hi,lo)
struct Frag { bf16x8 ah, al, bh[4], bl[4]; };

__device__ __forceinline__ void mmfrag(const Frag& f, f32x4* aHH, f32x4* aLH, f32x4* aHL){
  #pragma unroll
  for (int q=0;q<4;q++){
    aHH[q] = __builtin_amdgcn_mfma_f32_16x16x32_bf16(f.ah, f.bh[q], aHH[q],0,0,0);
    aLH[q] = __builtin_amdgcn_mfma_f32_16x16x32_bf16(f.al, f.bh[q], aLH[q],0,0,0);
    aHL[q] = __builtin_amdgcn_mfma_f32_16x16x32_bf16(f.ah, f.bl[q], aHL[q],0,0,0);
  }
}

// Pack W[G][K] (fp32, row-major) into MFMA-fragment-linear bf16 hi/lo.
__global__ void pack_w(const float* __restrict__ W, int G, int K, int KTtot, int kt0,
                       unsigned short* __restrict__ hi, unsigned short* __restrict__ lo){
  int idx = blockIdx.x*blockDim.x + threadIdx.x;
  int kt_n = K/32;
  int total = (G/16)*kt_n*64;
  if (idx >= total) return;
  int lane = idx & 63;
  int ktl = (idx>>6) % kt_n;
  int gt  = (idx>>6) / kt_n;
  int g = gt*16 + (lane & 15);
  int k = ktl*32 + (lane>>4)*8;
  const float* src = W + (size_t)g*K + k;
  size_t dst = (((size_t)gt*KTtot + (kt0 + ktl))*64 + lane)*8;
  #pragma unroll
  for (int j=0;j<8;j++){
    float x = src[j];
    unsigned short h = f2bf(x);
    hi[dst+j] = h;
    lo[dst+j] = f2bf(x - bf2f(h));
  }
}

// embedding projections (vocab=5)
__global__ void embprep(const float* __restrict__ emb,
                        const float* __restrict__ c0Wih, const float* __restrict__ c0b,
                        const float* __restrict__ g0Wih, const float* __restrict__ g0b,
                        float* __restrict__ ectx0, float* __restrict__ egen0){
  int idx = blockIdx.x*blockDim.x + threadIdx.x;
  if (idx < 2*5*1024){
    int d = idx / 5120;
    int v = (idx / 1024) % 5;
    int j = idx % 1024;
    const float* w = c0Wih + ((size_t)d*1024 + j)*64;
    const float* e = emb + v*64;
    float s = c0b[d*1024 + j];
    #pragma unroll
    for (int k=0;k<64;k++) s += e[k]*w[k];
    ectx0[idx] = s;
  } else if (idx < 2*5*1024 + 5*2048){
    int i2 = idx - 10240;
    int v = i2 / 2048;
    int j = i2 % 2048;
    const float* w = g0Wih + (size_t)j*64;
    const float* e = emb + v*64;
    float s = g0b[j];
    #pragma unroll
    for (int k=0;k<64;k++) s += e[k]*w[k];
    egen0[i2] = s;
  }
}

// prefill output logits with bias (atomic partials add onto this)
__global__ void prefill_out(float* __restrict__ out, const float* __restrict__ outb){
  int i = blockIdx.x*blockDim.x + threadIdx.x;
  if (i < BATCH*TDEC*5) out[i] = outb[i%5];
}

// ---------------- context layer 0 (MFMA) ---------------- (unchanged R3)
__global__ void __launch_bounds__(512,1) ctx_l0_mfma(
    const int* __restrict__ toks,
    const float* __restrict__ ectx0,
    const unsigned short* __restrict__ wh, const unsigned short* __restrict__ wl,
    unsigned short* __restrict__ y0h, unsigned short* __restrict__ y0l)
{
  const int id  = blockIdx.x;
  const int dir = (id >> 2) & 1;
  const int bx  = ((id >> 3) << 2) | (id & 3);
  const int e0  = bx * 16;
  const int lane = threadIdx.x & 63;
  const int w    = threadIdx.x >> 6;
  const int lo16 = lane & 15, kgrp = lane >> 4;

  __shared__ unsigned short hsh[16*256];
  __shared__ unsigned short hsl[16*256];
  __shared__ float cs[16*256];
  for (int i=threadIdx.x;i<16*256;i+=512){ hsh[i]=0; hsl[i]=0; cs[i]=0.f; }
  __syncthreads();

  const unsigned short* pbh[4][2];
  const unsigned short* pbl[4][2];
  #pragma unroll
  for (int g=0;g<4;g++){
    #pragma unroll
    for (int st=0;st<2;st++){
      int ct = g*16 + w*2 + st;
      size_t off = (size_t)dir*1024*256 + ((size_t)(ct*8)*64 + lane)*8;
      pbh[g][st] = wh + off; pbl[g][st] = wl + off;
    }
  }
  const unsigned aoff0 = (unsigned)(lo16*512 + kgrp*16);
  const unsigned axor  = ((unsigned)(lo16 & 7)) << 4;

  for (int s=0;s<L_SEQ;s++){
    const int t = dir ? (L_SEQ-1-s) : s;
    f32x4 zero = {0.f,0.f,0.f,0.f};
    f32x4 acc[4][2];
    #pragma unroll
    for (int g=0;g<4;g++){
      #pragma unroll
      for (int st=0;st<2;st++) acc[g][st] = zero;
    }
    #pragma unroll 2
    for (int kt=0;kt<8;kt++){
      unsigned ao = (aoff0 + kt*64) ^ axor;
      bf16x8 ah = *(const bf16x8*)((const char*)hsh + ao);
      bf16x8 al = *(const bf16x8*)((const char*)hsl + ao);
      #pragma unroll
      for (int g=0;g<4;g++){
        #pragma unroll
        for (int st=0;st<2;st++){
          bf16x8 bh = *(const bf16x8*)(pbh[g][st] + (size_t)kt*512);
          bf16x8 bl = *(const bf16x8*)(pbl[g][st] + (size_t)kt*512);
          acc[g][st] = __builtin_amdgcn_mfma_f32_16x16x32_bf16(ah,bh,acc[g][st],0,0,0);
          acc[g][st] = __builtin_amdgcn_mfma_f32_16x16x32_bf16(al,bh,acc[g][st],0,0,0);
          acc[g][st] = __builtin_amdgcn_mfma_f32_16x16x32_bf16(ah,bl,acc[g][st],0,0,0);
        }
      }
    }
    __syncthreads();
    int tkr[4];
    #pragma unroll
    for (int r=0;r<4;r++) tkr[r] = toks[(e0 + kgrp*4 + r)*L_SEQ + t];
    #pragma unroll
    for (int st=0;st<2;st++){
      const int unit = w*32 + st*16 + lo16;
      #pragma unroll
      for (int r=0;r<4;r++){
        const int row = kgrp*4 + r;
        const int e = e0 + row;
        const float* ep = ectx0 + ((size_t)(dir*5 + tkr[r]))*1024 + unit;
        float zi = acc[0][st][r] + ep[0];
        float zf = acc[1][st][r] + ep[256];
        float zg = acc[2][st][r] + ep[512];
        float zo = acc[3][st][r] + ep[768];
        int ci = row*256 + unit;
        float c = sigf(zf)*cs[ci] + sigf(zi)*tanhf(zg);
        float h = sigf(zo)*tanhf(c);
        cs[ci] = c;
        unsigned short hb = f2bf(h), lb = f2bf(h - bf2f(hb));
        unsigned hoff = ((unsigned)(row*512 + unit*2)) ^ (((unsigned)(row & 7)) << 4);
        *(unsigned short*)((char*)hsh + hoff) = hb;
        *(unsigned short*)((char*)hsl + hoff) = lb;
        size_t yo = ((size_t)t*BATCH + e)*512 + dir*256 + unit;
        y0h[yo] = hb; y0l[yo] = lb;
      }
    }
    __syncthreads();
  }
}

// ---------------- context layer 1 (MFMA) ---------------- (unchanged R3)
__global__ void __launch_bounds__(512,1) ctx_l1_mfma(
    const unsigned short* __restrict__ y0h, const unsigned short* __restrict__ y0l,
    const unsigned short* __restrict__ wh, const unsigned short* __restrict__ wl,
    const float* __restrict__ bias,
    float* __restrict__ finals, int t_store)
{
  const int id  = blockIdx.x;
  const int dir = (id >> 2) & 1;
  const int bx  = ((id >> 3) << 2) | (id & 3);
  const int e0  = bx * 16;
  const int lane = threadIdx.x & 63;
  const int w    = threadIdx.x >> 6;
  const int lo16 = lane & 15, kgrp = lane >> 4;

  __shared__ unsigned short xsh[16*512];
  __shared__ unsigned short xsl[16*512];
  __shared__ unsigned short hsh[16*256];
  __shared__ unsigned short hsl[16*256];
  __shared__ float cs[16*256];
  for (int i=threadIdx.x;i<16*256;i+=512){ hsh[i]=0; hsl[i]=0; cs[i]=0.f; }

  float bb[4][2];
  #pragma unroll
  for (int g=0;g<4;g++){
    #pragma unroll
    for (int st=0;st<2;st++)
      bb[g][st] = bias[dir*1024 + g*256 + w*32 + st*16 + lo16];
  }
  const unsigned short* pbh[4][2];
  const unsigned short* pbl[4][2];
  #pragma unroll
  for (int g=0;g<4;g++){
    #pragma unroll
    for (int st=0;st<2;st++){
      int ct = g*16 + w*2 + st;
      size_t off = (size_t)dir*1024*768 + ((size_t)(ct*24)*64 + lane)*8;
      pbh[g][st] = wh + off; pbl[g][st] = wl + off;
    }
  }
  const unsigned axor = ((unsigned)(lo16 & 7)) << 4;
  __syncthreads();

  for (int s=0;s<L_SEQ;s++){
    const int t = dir ? (L_SEQ-1-s) : s;
    #pragma unroll
    for (int cc=0; cc<2; cc++){
      int ci = threadIdx.x + cc*512;
      int row = ci >> 6, cr = ci & 63;
      const unsigned short* srcbase = y0h + ((size_t)t*BATCH + e0 + row)*512 + cr*8;
      const unsigned short* srcbasel = y0l + ((size_t)t*BATCH + e0 + row)*512 + cr*8;
      uint4 vh = *(const uint4*)srcbase;
      uint4 vl = *(const uint4*)srcbasel;
      unsigned xo = ((unsigned)(row*1024 + cr*16)) ^ (((unsigned)(row & 7)) << 4);
      *(uint4*)((char*)xsh + xo) = vh;
      *(uint4*)((char*)xsl + xo) = vl;
    }
    __syncthreads();
    f32x4 zero = {0.f,0.f,0.f,0.f};
    f32x4 acc[4][2];
    #pragma unroll
    for (int g=0;g<4;g++){
      #pragma unroll
      for (int st=0;st<2;st++) acc[g][st] = zero;
    }
    #pragma unroll 2
    for (int kt=0;kt<16;kt++){
      unsigned ao = ((unsigned)(lo16*1024 + kt*64 + kgrp*16)) ^ axor;
      bf16x8 ah = *(const bf16x8*)((const char*)xsh + ao);
      bf16x8 al = *(const bf16x8*)((const char*)xsl + ao);
      #pragma unroll
      for (int g=0;g<4;g++){
        #pragma unroll
        for (int st=0;st<2;st++){
          bf16x8 bh = *(const bf16x8*)(pbh[g][st] + (size_t)kt*512);
          bf16x8 bl = *(const bf16x8*)(pbl[g][st] + (size_t)kt*512);
          acc[g][st] = __builtin_amdgcn_mfma_f32_16x16x32_bf16(ah,bh,acc[g][st],0,0,0);
          acc[g][st] = __builtin_amdgcn_mfma_f32_16x16x32_bf16(al,bh,acc[g][st],0,0,0);
          acc[g][st] = __builtin_amdgcn_mfma_f32_16x16x32_bf16(ah,bl,acc[g][st],0,0,0);
        }
      }
    }
    #pragma unroll 2
    for (int kt=16;kt<24;kt++){
      unsigned ao = ((unsigned)(lo16*512 + (kt-16)*64 + kgrp*16)) ^ axor;
      bf16x8 ah = *(const bf16x8*)((const char*)hsh + ao);
      bf16x8 al = *(const bf16x8*)((const char*)hsl + ao);
      #pragma unroll
      for (int g=0;g<4;g++){
        #pragma unroll
        for (int st=0;st<2;st++){
          bf16x8 bh = *(const bf16x8*)(pbh[g][st] + (size_t)kt*512);
          bf16x8 bl = *(const bf16x8*)(pbl[g][st] + (size_t)kt*512);
          acc[g][st] = __builtin_amdgcn_mfma_f32_16x16x32_bf16(ah,bh,acc[g][st],0,0,0);
          acc[g][st] = __builtin_amdgcn_mfma_f32_16x16x32_bf16(al,bh,acc[g][st],0,0,0);
          acc[g][st] = __builtin_amdgcn_mfma_f32_16x16x32_bf16(ah,bl,acc[g][st],0,0,0);
        }
      }
    }
    __syncthreads();
    #pragma unroll
    for (int st=0;st<2;st++){
      const int unit = w*32 + st*16 + lo16;
      #pragma unroll
      for (int r=0;r<4;r++){
        const int row = kgrp*4 + r;
        float zi = acc[0][st][r] + bb[0][st];
        float zf = acc[1][st][r] + bb[1][st];
        float zg = acc[2][st][r] + bb[2][st];
        float zo = acc[3][st][r] + bb[3][st];
        int ci = row*256 + unit;
        float c = sigf(zf)*cs[ci] + sigf(zi)*tanhf(zg);
        float h = sigf(zo)*tanhf(c);
        cs[ci] = c;
        unsigned short hb = f2bf(h), lb = f2bf(h - bf2f(hb));
        unsigned hoff = ((unsigned)(row*512 + unit*2)) ^ (((unsigned)(row & 7)) << 4);
        *(unsigned short*)((char*)hsh + hoff) = hb;
        *(unsigned short*)((char*)hsl + hoff) = lb;
        if (t == t_store)
          finals[(size_t)(e0 + row)*512 + dir*256 + unit] = h;
      }
    }
    __syncthreads();
  }
}

__global__ void combine_init2(const float* __restrict__ lf, const float* __restrict__ rf,
                              unsigned short* __restrict__ h0h, unsigned short* __restrict__ h0l,
                              unsigned short* __restrict__ h1h, unsigned short* __restrict__ h1l,
                              float* __restrict__ c0, float* __restrict__ c1){
  int i = blockIdx.x*blockDim.x + threadIdx.x;
  if (i < BATCH*HG){
    float v = 0.5f*(lf[i]+rf[i]);
    unsigned short h = f2bf(v);
    unsigned short l = f2bf(v - bf2f(h));
    h0h[i]=h; h0l[i]=l; h1h[i]=h; h1l[i]=l;
    c0[i]=0.f; c1[i]=0.f;
  }
}

// ---------------- decoder layer 0 (pipelined MFMA + inline argmax) ----------
// 256 blocks x 512 thr. by=bid&15 (weight slice, XCD-local); bx=bid>>4 (rows).
__global__ void __launch_bounds__(512,2) dec_l0_mfma(
    const float* __restrict__ out,            // logits of step t-1
    const float* __restrict__ egen0,
    const unsigned short* __restrict__ wh, const unsigned short* __restrict__ wl,
    const unsigned short* __restrict__ hih, const unsigned short* __restrict__ hil,
    unsigned short* __restrict__ hoh, unsigned short* __restrict__ hol,
    float* __restrict__ cst, int t)
{
  const int bid = blockIdx.x;
  const int by = bid & 15;
  const int bx = bid >> 4;
  const int e0 = bx * 64;
  const int lane = threadIdx.x & 63;
  const int w = threadIdx.x >> 6;
  const int wm = w & 3, wu = w >> 2;
  const int ut = by*2 + wu;
  const int lo16 = lane & 15, kgrp = lane >> 4;
  const int arow = e0 + wm*16 + lo16;
  const int u = ut*16 + lo16;
  const int r0 = e0 + wm*16 + kgrp*4;

  const unsigned short* pah = hih + (size_t)arow*512 + kgrp*8;
  const unsigned short* pal = hil + (size_t)arow*512 + kgrp*8;
  const unsigned short* pb[8];
  #pragma unroll
  for (int q=0;q<4;q++){
    size_t off = ((size_t)(q*32+ut)*16*64 + lane)*8;   // KT=16
    pb[q]   = wh + off;
    pb[q+4] = wl + off;
  }
  const f32x4 z4 = {0.f,0.f,0.f,0.f};
  f32x4 aHH[4]={z4,z4,z4,z4}, aLH[4]={z4,z4,z4,z4}, aHL[4]={z4,z4,z4,z4};

  Frag f0, f1;
  // prologue: load ks=0
  f0.ah = *(const bf16x8*)(pah);
  f0.al = *(const bf16x8*)(pal);
  #pragma unroll
  for (int q=0;q<4;q++){
    f0.bh[q] = *(const bf16x8*)(pb[q]);
    f0.bl[q] = *(const bf16x8*)(pb[q+4]);
  }
  #pragma unroll
  for (int ks=0; ks<16; ks+=2){
    // load ks+1 before consuming ks (>=20 loads in flight)
    f1.ah = *(const bf16x8*)(pah + (size_t)(ks+1)*32);
    f1.al = *(const bf16x8*)(pal + (size_t)(ks+1)*32);
    #pragma unroll
    for (int q=0;q<4;q++){
      f1.bh[q] = *(const bf16x8*)(pb[q]   + (size_t)(ks+1)*512);
      f1.bl[q] = *(const bf16x8*)(pb[q+4] + (size_t)(ks+1)*512);
    }
    mmfrag(f0, aHH, aLH, aHL);
    if (ks+2 < 16){
      f0.ah = *(const bf16x8*)(pah + (size_t)(ks+2)*32);
      f0.al = *(const bf16x8*)(pal + (size_t)(ks+2)*32);
      #pragma unroll
      for (int q=0;q<4;q++){
        f0.bh[q] = *(const bf16x8*)(pb[q]   + (size_t)(ks+2)*512);
        f0.bl[q] = *(const bf16x8*)(pb[q+4] + (size_t)(ks+2)*512);
      }
    }
    mmfrag(f1, aHH, aLH, aHL);
  }

  // inline argmax of previous step's logits (bias-prefilled + atomic partials)
  int tkr[4];
  #pragma unroll
  for (int r=0;r<4;r++){
    int tk = 0;
    if (t > 0){
      const float* lp = out + ((size_t)(r0+r)*TDEC + (t-1))*5;
      float l0=lp[0],l1=lp[1],l2=lp[2],l3=lp[3],l4=lp[4];
      float best=l0;
      if (l1>best){best=l1;tk=1;}
      if (l2>best){best=l2;tk=2;}
      if (l3>best){best=l3;tk=3;}
      if (l4>best){best=l4;tk=4;}
    }
    tkr[r]=tk;
  }
  #pragma unroll
  for (int r=0;r<4;r++){
    const int e = r0 + r;
    const float* ep = egen0 + (size_t)tkr[r]*2048 + u;
    float zi = aHH[0][r]+aLH[0][r]+aHL[0][r] + ep[0];
    float zf = aHH[1][r]+aLH[1][r]+aHL[1][r] + ep[512];
    float zg = aHH[2][r]+aLH[2][r]+aHL[2][r] + ep[1024];
    float zo = aHH[3][r]+aLH[3][r]+aHL[3][r] + ep[1536];
    const size_t idx = (size_t)e*512 + u;
    float c = sigf(zf)*cst[idx] + sigf(zi)*tanhf(zg);
    float h = sigf(zo)*tanhf(c);
    cst[idx] = c;
    unsigned short hb = f2bf(h);
    hoh[idx] = hb;
    hol[idx] = f2bf(h - bf2f(hb));
  }
}

// ------------- decoder layer 1 + fused logits (pipelined MFMA) --------------
__global__ void __launch_bounds__(512,2) dec_l1_mfma(
    const unsigned short* __restrict__ xh, const unsigned short* __restrict__ xl,
    const unsigned short* __restrict__ wh, const unsigned short* __restrict__ wl,
    const float* __restrict__ bias,
    const unsigned short* __restrict__ hih, const unsigned short* __restrict__ hil,
    unsigned short* __restrict__ hoh, unsigned short* __restrict__ hol,
    float* __restrict__ cst,
    const float* __restrict__ outW,
    float* __restrict__ out, int t)
{
  const int bid = blockIdx.x;
  const int by = bid & 15;
  const int bx = bid >> 4;
  const int e0 = bx * 64;
  const int lane = threadIdx.x & 63;
  const int w = threadIdx.x >> 6;
  const int wm = w & 3, wu = w >> 2;
  const int ut = by*2 + wu;
  const int lo16 = lane & 15, kgrp = lane >> 4;
  const int arow = e0 + wm*16 + lo16;
  const int u = ut*16 + lo16;
  const int r0 = e0 + wm*16 + kgrp*4;

  const unsigned short* pxh = xh  + (size_t)arow*512 + kgrp*8;
  const unsigned short* pxl = xl  + (size_t)arow*512 + kgrp*8;
  const unsigned short* pah = hih + (size_t)arow*512 + kgrp*8;
  const unsigned short* pal = hil + (size_t)arow*512 + kgrp*8;
  const unsigned short* pb[8];
  #pragma unroll
  for (int q=0;q<4;q++){
    size_t off = ((size_t)(q*32+ut)*32*64 + lane)*8;   // KT=32
    pb[q]   = wh + off;
    pb[q+4] = wl + off;
  }
  const f32x4 z4 = {0.f,0.f,0.f,0.f};
  f32x4 aHH[4]={z4,z4,z4,z4}, aLH[4]={z4,z4,z4,z4}, aHL[4]={z4,z4,z4,z4};

  Frag f0, f1;
  // A-source select is compile-time after full unroll: ks<16 -> x, else h1prev
#define DEC1_LDA(F, KS) \
  { if ((KS) < 16){ F.ah = *(const bf16x8*)(pxh + (size_t)(KS)*32); \
                    F.al = *(const bf16x8*)(pxl + (size_t)(KS)*32); } \
    else          { F.ah = *(const bf16x8*)(pah + (size_t)((KS)-16)*32); \
                    F.al = *(const bf16x8*)(pal + (size_t)((KS)-16)*32); } \
    _Pragma("unroll") \
    for (int q=0;q<4;q++){ \
      F.bh[q] = *(const bf16x8*)(pb[q]   + (size_t)(KS)*512); \
      F.bl[q] = *(const bf16x8*)(pb[q+4] + (size_t)(KS)*512); } }

  DEC1_LDA(f0, 0);
  #pragma unroll
  for (int ks=0; ks<32; ks+=2){
    DEC1_LDA(f1, ks+1);
    mmfrag(f0, aHH, aLH, aHL);
    if (ks+2 < 32){ DEC1_LDA(f0, ks+2); }
    mmfrag(f1, aHH, aLH, aHL);
  }
#undef DEC1_LDA

  const float b0 = bias[u], b1 = bias[512+u], b2 = bias[1024+u], b3 = bias[1536+u];
  float ow[5];
  #pragma unroll
  for (int v=0;v<5;v++) ow[v] = outW[v*512 + u];

  float hv[4];
  #pragma unroll
  for (int r=0;r<4;r++){
    const int e = r0 + r;
    float zi = aHH[0][r]+aLH[0][r]+aHL[0][r] + b0;
    float zf = aHH[1][r]+aLH[1][r]+aHL[1][r] + b1;
    float zg = aHH[2][r]+aLH[2][r]+aHL[2][r] + b2;
    float zo = aHH[3][r]+aLH[3][r]+aHL[3][r] + b3;
    const size_t idx = (size_t)e*512 + u;
    float c = sigf(zf)*cst[idx] + sigf(zi)*tanhf(zg);
    float h = sigf(zo)*tanhf(c);
    cst[idx] = c;
    hv[r] = h;
    unsigned short hb = f2bf(h);
    hoh[idx] = hb;
    hol[idx] = f2bf(h - bf2f(hb));
  }
  // partial logits: reduce over 16 lanes (units of this tile), atomicAdd
  #pragma unroll
  for (int r=0;r<4;r++){
    #pragma unroll
    for (int v=0;v<5;v++){
      float psum = hv[r]*ow[v];
      psum += __shfl_xor(psum, 1);
      psum += __shfl_xor(psum, 2);
      psum += __shfl_xor(psum, 4);
      psum += __shfl_xor(psum, 8);
      if (lo16 == 0)
        atomicAdd(out + ((size_t)(r0+r)*TDEC + t)*5 + v, psum);
    }
  }
}

extern "C" void kernel_launch(void* const* d_in, const int* in_sizes, int n_in,
                              void* d_out, int out_size, void* d_ws, size_t ws_size,
                              hipStream_t stream){
  (void)in_sizes; (void)n_in; (void)out_size;
  const int*   leftc    = (const int*)d_in[0];
  const int*   rightc   = (const int*)d_in[1];
  const float* emb      = (const float*)d_in[3];
  const float* ctx0_Wih = (const float*)d_in[4];
  const float* ctx0_Whh = (const float*)d_in[5];
  const float* ctx0_b   = (const float*)d_in[6];
  const float* ctx1_Wih = (const float*)d_in[7];
  const float* ctx1_Whh = (const float*)d_in[8];
  const float* ctx1_b   = (const float*)d_in[9];
  const float* gen0_Wih = (const float*)d_in[10];
  const float* gen0_Whh = (const float*)d_in[11];
  const float* gen0_b   = (const float*)d_in[12];
  const float* gen1_Wih = (const float*)d_in[13];
  const float* gen1_Whh = (const float*)d_in[14];
  const float* gen1_b   = (const float*)d_in[15];
  const float* out_W    = (const float*)d_in[16];
  const float* out_b    = (const float*)d_in[17];
  float* out = (float*)d_out;

  char* p = (char*)d_ws;
  auto carve = [&](size_t nfloats)->float*{
    float* r = (float*)p;
    p += ((nfloats*sizeof(float) + 255) & ~(size_t)255);
    return r;
  };
  auto carveu = [&](size_t nush)->unsigned short*{
    return (unsigned short*)carve((nush + 1)/2);
  };
  float* ectx0  = carve(2*5*1024);
  float* egen0  = carve(5*2048);
  float* leftF  = carve((size_t)BATCH*HG);
  float* rightF = carve((size_t)BATCH*HG);
  float* c0s    = carve((size_t)BATCH*HG);
  float* c1s    = carve((size_t)BATCH*HG);
  unsigned short* c0pkh = carveu((size_t)2*1024*256);
  unsigned short* c0pkl = carveu((size_t)2*1024*256);
  unsigned short* c1pkh = carveu((size_t)2*1024*768);
  unsigned short* c1pkl = carveu((size_t)2*1024*768);
  unsigned short* pk0h = carveu((size_t)2048*512);
  unsigned short* pk0l = carveu((size_t)2048*512);
  unsigned short* pk1h = carveu((size_t)2048*1024);
  unsigned short* pk1l = carveu((size_t)2048*1024);
  unsigned short* h0ha = carveu((size_t)BATCH*HG);
  unsigned short* h0la = carveu((size_t)BATCH*HG);
  unsigned short* h0hb = carveu((size_t)BATCH*HG);
  unsigned short* h0lb = carveu((size_t)BATCH*HG);
  unsigned short* h1ha = carveu((size_t)BATCH*HG);
  unsigned short* h1la = carveu((size_t)BATCH*HG);
  unsigned short* h1hb = carveu((size_t)BATCH*HG);
  unsigned short* h1lb = carveu((size_t)BATCH*HG);
  unsigned short* y0h = carveu((size_t)L_SEQ*BATCH*512);   // 105 MB
  unsigned short* y0l = carveu((size_t)L_SEQ*BATCH*512);   // 105 MB
  if ((size_t)(p - (char*)d_ws) > ws_size) return;  // insufficient workspace -> loud fail

  // weight packs (fragment-linear bf16 hi/lo)
  for (int d=0; d<2; d++){
    pack_w<<<128, 256, 0, stream>>>(ctx0_Whh + (size_t)d*1024*256, 1024, 256, 8, 0,
                                    c0pkh + (size_t)d*262144, c0pkl + (size_t)d*262144);
    pack_w<<<256, 256, 0, stream>>>(ctx1_Wih + (size_t)d*1024*512, 1024, 512, 24, 0,
                                    c1pkh + (size_t)d*786432, c1pkl + (size_t)d*786432);
    pack_w<<<128, 256, 0, stream>>>(ctx1_Whh + (size_t)d*1024*256, 1024, 256, 24, 16,
                                    c1pkh + (size_t)d*786432, c1pkl + (size_t)d*786432);
  }
  pack_w<<<512, 256, 0, stream>>>(gen0_Whh, 2048, 512, 16,  0, pk0h, pk0l);
  pack_w<<<512, 256, 0, stream>>>(gen1_Wih, 2048, 512, 32,  0, pk1h, pk1l);
  pack_w<<<512, 256, 0, stream>>>(gen1_Whh, 2048, 512, 32, 16, pk1h, pk1l);

  embprep<<<(20480+255)/256, 256, 0, stream>>>(emb, ctx0_Wih, ctx0_b,
                                               gen0_Wih, gen0_b, ectx0, egen0);
  prefill_out<<<(BATCH*TDEC*5+255)/256, 256, 0, stream>>>(out, out_b);

  // left encode (finals at t=99), then right (finals at t=0); y0 reused
  ctx_l0_mfma<<<128, 512, 0, stream>>>(leftc, ectx0, c0pkh, c0pkl, y0h, y0l);
  ctx_l1_mfma<<<128, 512, 0, stream>>>(y0h, y0l, c1pkh, c1pkl, ctx1_b, leftF, L_SEQ-1);
  ctx_l0_mfma<<<128, 512, 0, stream>>>(rightc, ectx0, c0pkh, c0pkl, y0h, y0l);
  ctx_l1_mfma<<<128, 512, 0, stream>>>(y0h, y0l, c1pkh, c1pkl, ctx1_b, rightF, 0);

  combine_init2<<<(BATCH*HG+255)/256, 256, 0, stream>>>(leftF, rightF,
                                                        h0ha, h0la, h1ha, h1la,
                                                        c0s, c1s);

  for (int t=0;t<TDEC;t++){
    unsigned short* h0ih = (t&1)? h0hb : h0ha;
    unsigned short* h0il = (t&1)? h0lb : h0la;
    unsigned short* h0oh = (t&1)? h0ha : h0hb;
    unsigned short* h0ol = (t&1)? h0la : h0lb;
    unsigned short* h1ih = (t&1)? h1hb : h1ha;
    unsigned short* h1il = (t&1)? h1lb : h1la;
    unsigned short* h1oh = (t&1)? h1ha : h1hb;
    unsigned short* h1ol = (t&1)? h1la : h1lb;
    dec_l0_mfma<<<256, 512, 0, stream>>>(out, egen0, pk0h, pk0l,
                                         h0ih, h0il, h0oh, h0ol, c0s, t);
    dec_l1_mfma<<<256, 512, 0, stream>>>(h0oh, h0ol, pk1h, pk1l, gen1_b,
                                         h1ih, h1il, h1oh, h1ol, c1s,
                                         out_W, out, t);
  }
}

// Round 5
// 31709.290 us; speedup vs baseline: 1.4401x; 1.0782x over previous
//
#include <hip/hip_runtime.h>

// LSTMGapFiller R6: revert R5's manual Frag double-buffer (regression suspect:
// ~80 staged VGPRs + full unroll beat the compiler's own scheduling, guide
// mistake #5). Decoder main loops back to R3-proven compiler-scheduled form
// (unroll 2), KEEPING R5's wins: 12 indep acc chains, argmax fused into dec_l0,
// logits fused into dec_l1 (shfl + atomicAdd onto bias-prefilled out; dec_out
// kernel deleted). dec_l1 K-loop split into two independent per-iter streams
// (x at ks, h at ks+16) for free dual-chain ILP. Context stack unchanged (R3).

#define L_SEQ 100
#define BATCH 1024
#define HCTX 256
#define HG 512
#define TDEC 256

typedef __attribute__((ext_vector_type(8))) short bf16x8;
typedef __attribute__((ext_vector_type(4))) float f32x4;

__device__ __forceinline__ float sigf(float x){ return 1.0f/(1.0f+expf(-x)); }
__device__ __forceinline__ unsigned short f2bf(float x){
  unsigned int u = __float_as_uint(x);
  return (unsigned short)((u + 0x7fffu + ((u>>16)&1u)) >> 16);   // RNE
}
__device__ __forceinline__ float bf2f(unsigned short h){
  return __uint_as_float(((unsigned int)h)<<16);
}

// Pack W[G][K] (fp32, row-major) into MFMA-fragment-linear bf16 hi/lo.
__global__ void pack_w(const float* __restrict__ W, int G, int K, int KTtot, int kt0,
                       unsigned short* __restrict__ hi, unsigned short* __restrict__ lo){
  int idx = blockIdx.x*blockDim.x + threadIdx.x;
  int kt_n = K/32;
  int total = (G/16)*kt_n*64;
  if (idx >= total) return;
  int lane = idx & 63;
  int ktl = (idx>>6) % kt_n;
  int gt  = (idx>>6) / kt_n;
  int g = gt*16 + (lane & 15);
  int k = ktl*32 + (lane>>4)*8;
  const float* src = W + (size_t)g*K + k;
  size_t dst = (((size_t)gt*KTtot + (kt0 + ktl))*64 + lane)*8;
  #pragma unroll
  for (int j=0;j<8;j++){
    float x = src[j];
    unsigned short h = f2bf(x);
    hi[dst+j] = h;
    lo[dst+j] = f2bf(x - bf2f(h));
  }
}

// embedding projections (vocab=5)
__global__ void embprep(const float* __restrict__ emb,
                        const float* __restrict__ c0Wih, const float* __restrict__ c0b,
                        const float* __restrict__ g0Wih, const float* __restrict__ g0b,
                        float* __restrict__ ectx0, float* __restrict__ egen0){
  int idx = blockIdx.x*blockDim.x + threadIdx.x;
  if (idx < 2*5*1024){
    int d = idx / 5120;
    int v = (idx / 1024) % 5;
    int j = idx % 1024;
    const float* w = c0Wih + ((size_t)d*1024 + j)*64;
    const float* e = emb + v*64;
    float s = c0b[d*1024 + j];
    #pragma unroll
    for (int k=0;k<64;k++) s += e[k]*w[k];
    ectx0[idx] = s;
  } else if (idx < 2*5*1024 + 5*2048){
    int i2 = idx - 10240;
    int v = i2 / 2048;
    int j = i2 % 2048;
    const float* w = g0Wih + (size_t)j*64;
    const float* e = emb + v*64;
    float s = g0b[j];
    #pragma unroll
    for (int k=0;k<64;k++) s += e[k]*w[k];
    egen0[i2] = s;
  }
}

// prefill output logits with bias (atomic partials add onto this)
__global__ void prefill_out(float* __restrict__ out, const float* __restrict__ outb){
  int i = blockIdx.x*blockDim.x + threadIdx.x;
  if (i < BATCH*TDEC*5) out[i] = outb[i%5];
}

// ---------------- context layer 0 (MFMA) ---------------- (unchanged R3)
__global__ void __launch_bounds__(512,1) ctx_l0_mfma(
    const int* __restrict__ toks,
    const float* __restrict__ ectx0,
    const unsigned short* __restrict__ wh, const unsigned short* __restrict__ wl,
    unsigned short* __restrict__ y0h, unsigned short* __restrict__ y0l)
{
  const int id  = blockIdx.x;
  const int dir = (id >> 2) & 1;
  const int bx  = ((id >> 3) << 2) | (id & 3);
  const int e0  = bx * 16;
  const int lane = threadIdx.x & 63;
  const int w    = threadIdx.x >> 6;
  const int lo16 = lane & 15, kgrp = lane >> 4;

  __shared__ unsigned short hsh[16*256];
  __shared__ unsigned short hsl[16*256];
  __shared__ float cs[16*256];
  for (int i=threadIdx.x;i<16*256;i+=512){ hsh[i]=0; hsl[i]=0; cs[i]=0.f; }
  __syncthreads();

  const unsigned short* pbh[4][2];
  const unsigned short* pbl[4][2];
  #pragma unroll
  for (int g=0;g<4;g++){
    #pragma unroll
    for (int st=0;st<2;st++){
      int ct = g*16 + w*2 + st;
      size_t off = (size_t)dir*1024*256 + ((size_t)(ct*8)*64 + lane)*8;
      pbh[g][st] = wh + off; pbl[g][st] = wl + off;
    }
  }
  const unsigned aoff0 = (unsigned)(lo16*512 + kgrp*16);
  const unsigned axor  = ((unsigned)(lo16 & 7)) << 4;

  for (int s=0;s<L_SEQ;s++){
    const int t = dir ? (L_SEQ-1-s) : s;
    f32x4 zero = {0.f,0.f,0.f,0.f};
    f32x4 acc[4][2];
    #pragma unroll
    for (int g=0;g<4;g++){
      #pragma unroll
      for (int st=0;st<2;st++) acc[g][st] = zero;
    }
    #pragma unroll 2
    for (int kt=0;kt<8;kt++){
      unsigned ao = (aoff0 + kt*64) ^ axor;
      bf16x8 ah = *(const bf16x8*)((const char*)hsh + ao);
      bf16x8 al = *(const bf16x8*)((const char*)hsl + ao);
      #pragma unroll
      for (int g=0;g<4;g++){
        #pragma unroll
        for (int st=0;st<2;st++){
          bf16x8 bh = *(const bf16x8*)(pbh[g][st] + (size_t)kt*512);
          bf16x8 bl = *(const bf16x8*)(pbl[g][st] + (size_t)kt*512);
          acc[g][st] = __builtin_amdgcn_mfma_f32_16x16x32_bf16(ah,bh,acc[g][st],0,0,0);
          acc[g][st] = __builtin_amdgcn_mfma_f32_16x16x32_bf16(al,bh,acc[g][st],0,0,0);
          acc[g][st] = __builtin_amdgcn_mfma_f32_16x16x32_bf16(ah,bl,acc[g][st],0,0,0);
        }
      }
    }
    __syncthreads();
    int tkr[4];
    #pragma unroll
    for (int r=0;r<4;r++) tkr[r] = toks[(e0 + kgrp*4 + r)*L_SEQ + t];
    #pragma unroll
    for (int st=0;st<2;st++){
      const int unit = w*32 + st*16 + lo16;
      #pragma unroll
      for (int r=0;r<4;r++){
        const int row = kgrp*4 + r;
        const int e = e0 + row;
        const float* ep = ectx0 + ((size_t)(dir*5 + tkr[r]))*1024 + unit;
        float zi = acc[0][st][r] + ep[0];
        float zf = acc[1][st][r] + ep[256];
        float zg = acc[2][st][r] + ep[512];
        float zo = acc[3][st][r] + ep[768];
        int ci = row*256 + unit;
        float c = sigf(zf)*cs[ci] + sigf(zi)*tanhf(zg);
        float h = sigf(zo)*tanhf(c);
        cs[ci] = c;
        unsigned short hb = f2bf(h), lb = f2bf(h - bf2f(hb));
        unsigned hoff = ((unsigned)(row*512 + unit*2)) ^ (((unsigned)(row & 7)) << 4);
        *(unsigned short*)((char*)hsh + hoff) = hb;
        *(unsigned short*)((char*)hsl + hoff) = lb;
        size_t yo = ((size_t)t*BATCH + e)*512 + dir*256 + unit;
        y0h[yo] = hb; y0l[yo] = lb;
      }
    }
    __syncthreads();
  }
}

// ---------------- context layer 1 (MFMA) ---------------- (unchanged R3)
__global__ void __launch_bounds__(512,1) ctx_l1_mfma(
    const unsigned short* __restrict__ y0h, const unsigned short* __restrict__ y0l,
    const unsigned short* __restrict__ wh, const unsigned short* __restrict__ wl,
    const float* __restrict__ bias,
    float* __restrict__ finals, int t_store)
{
  const int id  = blockIdx.x;
  const int dir = (id >> 2) & 1;
  const int bx  = ((id >> 3) << 2) | (id & 3);
  const int e0  = bx * 16;
  const int lane = threadIdx.x & 63;
  const int w    = threadIdx.x >> 6;
  const int lo16 = lane & 15, kgrp = lane >> 4;

  __shared__ unsigned short xsh[16*512];
  __shared__ unsigned short xsl[16*512];
  __shared__ unsigned short hsh[16*256];
  __shared__ unsigned short hsl[16*256];
  __shared__ float cs[16*256];
  for (int i=threadIdx.x;i<16*256;i+=512){ hsh[i]=0; hsl[i]=0; cs[i]=0.f; }

  float bb[4][2];
  #pragma unroll
  for (int g=0;g<4;g++){
    #pragma unroll
    for (int st=0;st<2;st++)
      bb[g][st] = bias[dir*1024 + g*256 + w*32 + st*16 + lo16];
  }
  const unsigned short* pbh[4][2];
  const unsigned short* pbl[4][2];
  #pragma unroll
  for (int g=0;g<4;g++){
    #pragma unroll
    for (int st=0;st<2;st++){
      int ct = g*16 + w*2 + st;
      size_t off = (size_t)dir*1024*768 + ((size_t)(ct*24)*64 + lane)*8;
      pbh[g][st] = wh + off; pbl[g][st] = wl + off;
    }
  }
  const unsigned axor = ((unsigned)(lo16 & 7)) << 4;
  __syncthreads();

  for (int s=0;s<L_SEQ;s++){
    const int t = dir ? (L_SEQ-1-s) : s;
    #pragma unroll
    for (int cc=0; cc<2; cc++){
      int ci = threadIdx.x + cc*512;
      int row = ci >> 6, cr = ci & 63;
      const unsigned short* srcbase = y0h + ((size_t)t*BATCH + e0 + row)*512 + cr*8;
      const unsigned short* srcbasel = y0l + ((size_t)t*BATCH + e0 + row)*512 + cr*8;
      uint4 vh = *(const uint4*)srcbase;
      uint4 vl = *(const uint4*)srcbasel;
      unsigned xo = ((unsigned)(row*1024 + cr*16)) ^ (((unsigned)(row & 7)) << 4);
      *(uint4*)((char*)xsh + xo) = vh;
      *(uint4*)((char*)xsl + xo) = vl;
    }
    __syncthreads();
    f32x4 zero = {0.f,0.f,0.f,0.f};
    f32x4 acc[4][2];
    #pragma unroll
    for (int g=0;g<4;g++){
      #pragma unroll
      for (int st=0;st<2;st++) acc[g][st] = zero;
    }
    #pragma unroll 2
    for (int kt=0;kt<16;kt++){
      unsigned ao = ((unsigned)(lo16*1024 + kt*64 + kgrp*16)) ^ axor;
      bf16x8 ah = *(const bf16x8*)((const char*)xsh + ao);
      bf16x8 al = *(const bf16x8*)((const char*)xsl + ao);
      #pragma unroll
      for (int g=0;g<4;g++){
        #pragma unroll
        for (int st=0;st<2;st++){
          bf16x8 bh = *(const bf16x8*)(pbh[g][st] + (size_t)kt*512);
          bf16x8 bl = *(const bf16x8*)(pbl[g][st] + (size_t)kt*512);
          acc[g][st] = __builtin_amdgcn_mfma_f32_16x16x32_bf16(ah,bh,acc[g][st],0,0,0);
          acc[g][st] = __builtin_amdgcn_mfma_f32_16x16x32_bf16(al,bh,acc[g][st],0,0,0);
          acc[g][st] = __builtin_amdgcn_mfma_f32_16x16x32_bf16(ah,bl,acc[g][st],0,0,0);
        }
      }
    }
    #pragma unroll 2
    for (int kt=16;kt<24;kt++){
      unsigned ao = ((unsigned)(lo16*512 + (kt-16)*64 + kgrp*16)) ^ axor;
      bf16x8 ah = *(const bf16x8*)((const char*)hsh + ao);
      bf16x8 al = *(const bf16x8*)((const char*)hsl + ao);
      #pragma unroll
      for (int g=0;g<4;g++){
        #pragma unroll
        for (int st=0;st<2;st++){
          bf16x8 bh = *(const bf16x8*)(pbh[g][st] + (size_t)kt*512);
          bf16x8 bl = *(const bf16x8*)(pbl[g][st] + (size_t)kt*512);
          acc[g][st] = __builtin_amdgcn_mfma_f32_16x16x32_bf16(ah,bh,acc[g][st],0,0,0);
          acc[g][st] = __builtin_amdgcn_mfma_f32_16x16x32_bf16(al,bh,acc[g][st],0,0,0);
          acc[g][st] = __builtin_amdgcn_mfma_f32_16x16x32_bf16(ah,bl,acc[g][st],0,0,0);
        }
      }
    }
    __syncthreads();
    #pragma unroll
    for (int st=0;st<2;st++){
      const int unit = w*32 + st*16 + lo16;
      #pragma unroll
      for (int r=0;r<4;r++){
        const int row = kgrp*4 + r;
        float zi = acc[0][st][r] + bb[0][st];
        float zf = acc[1][st][r] + bb[1][st];
        float zg = acc[2][st][r] + bb[2][st];
        float zo = acc[3][st][r] + bb[3][st];
        int ci = row*256 + unit;
        float c = sigf(zf)*cs[ci] + sigf(zi)*tanhf(zg);
        float h = sigf(zo)*tanhf(c);
        cs[ci] = c;
        unsigned short hb = f2bf(h), lb = f2bf(h - bf2f(hb));
        unsigned hoff = ((unsigned)(row*512 + unit*2)) ^ (((unsigned)(row & 7)) << 4);
        *(unsigned short*)((char*)hsh + hoff) = hb;
        *(unsigned short*)((char*)hsl + hoff) = lb;
        if (t == t_store)
          finals[(size_t)(e0 + row)*512 + dir*256 + unit] = h;
      }
    }
    __syncthreads();
  }
}

__global__ void combine_init2(const float* __restrict__ lf, const float* __restrict__ rf,
                              unsigned short* __restrict__ h0h, unsigned short* __restrict__ h0l,
                              unsigned short* __restrict__ h1h, unsigned short* __restrict__ h1l,
                              float* __restrict__ c0, float* __restrict__ c1){
  int i = blockIdx.x*blockDim.x + threadIdx.x;
  if (i < BATCH*HG){
    float v = 0.5f*(lf[i]+rf[i]);
    unsigned short h = f2bf(v);
    unsigned short l = f2bf(v - bf2f(h));
    h0h[i]=h; h0l[i]=l; h1h[i]=h; h1l[i]=l;
    c0[i]=0.f; c1[i]=0.f;
  }
}

// ---------------- decoder layer 0 (MFMA + inline argmax) --------------------
// 256 blocks x 512 thr. by=bid&15 (weight slice, XCD-local); bx=bid>>4 (rows).
// R3-proven compiler-scheduled loop; 12 independent acc chains.
__global__ void __launch_bounds__(512,2) dec_l0_mfma(
    const float* __restrict__ out,            // logits of step t-1
    const float* __restrict__ egen0,
    const unsigned short* __restrict__ wh, const unsigned short* __restrict__ wl,
    const unsigned short* __restrict__ hih, const unsigned short* __restrict__ hil,
    unsigned short* __restrict__ hoh, unsigned short* __restrict__ hol,
    float* __restrict__ cst, int t)
{
  const int bid = blockIdx.x;
  const int by = bid & 15;
  const int bx = bid >> 4;
  const int e0 = bx * 64;
  const int lane = threadIdx.x & 63;
  const int w = threadIdx.x >> 6;
  const int wm = w & 3, wu = w >> 2;
  const int ut = by*2 + wu;
  const int lo16 = lane & 15, kgrp = lane >> 4;
  const int arow = e0 + wm*16 + lo16;
  const int u = ut*16 + lo16;
  const int r0 = e0 + wm*16 + kgrp*4;

  const unsigned short* pah = hih + (size_t)arow*512 + kgrp*8;
  const unsigned short* pal = hil + (size_t)arow*512 + kgrp*8;
  const unsigned short* pb[8];
  #pragma unroll
  for (int q=0;q<4;q++){
    size_t off = ((size_t)(q*32+ut)*16*64 + lane)*8;   // KT=16
    pb[q]   = wh + off;
    pb[q+4] = wl + off;
  }
  const f32x4 z4 = {0.f,0.f,0.f,0.f};
  f32x4 aHH[4]={z4,z4,z4,z4}, aLH[4]={z4,z4,z4,z4}, aHL[4]={z4,z4,z4,z4};

  #pragma unroll 2
  for (int ks=0; ks<16; ks++){
    bf16x8 ah = *(const bf16x8*)(pah + (size_t)ks*32);
    bf16x8 al = *(const bf16x8*)(pal + (size_t)ks*32);
    #pragma unroll
    for (int q=0;q<4;q++){
      bf16x8 bh = *(const bf16x8*)(pb[q]   + (size_t)ks*512);
      bf16x8 bl = *(const bf16x8*)(pb[q+4] + (size_t)ks*512);
      aHH[q] = __builtin_amdgcn_mfma_f32_16x16x32_bf16(ah, bh, aHH[q], 0,0,0);
      aLH[q] = __builtin_amdgcn_mfma_f32_16x16x32_bf16(al, bh, aLH[q], 0,0,0);
      aHL[q] = __builtin_amdgcn_mfma_f32_16x16x32_bf16(ah, bl, aHL[q], 0,0,0);
    }
  }

  // inline argmax of previous step's logits (bias-prefilled + atomic partials)
  int tkr[4];
  #pragma unroll
  for (int r=0;r<4;r++){
    int tk = 0;
    if (t > 0){
      const float* lp = out + ((size_t)(r0+r)*TDEC + (t-1))*5;
      float l0=lp[0],l1=lp[1],l2=lp[2],l3=lp[3],l4=lp[4];
      float best=l0;
      if (l1>best){best=l1;tk=1;}
      if (l2>best){best=l2;tk=2;}
      if (l3>best){best=l3;tk=3;}
      if (l4>best){best=l4;tk=4;}
    }
    tkr[r]=tk;
  }
  #pragma unroll
  for (int r=0;r<4;r++){
    const int e = r0 + r;
    const float* ep = egen0 + (size_t)tkr[r]*2048 + u;
    float zi = aHH[0][r]+aLH[0][r]+aHL[0][r] + ep[0];
    float zf = aHH[1][r]+aLH[1][r]+aHL[1][r] + ep[512];
    float zg = aHH[2][r]+aLH[2][r]+aHL[2][r] + ep[1024];
    float zo = aHH[3][r]+aLH[3][r]+aHL[3][r] + ep[1536];
    const size_t idx = (size_t)e*512 + u;
    float c = sigf(zf)*cst[idx] + sigf(zi)*tanhf(zg);
    float h = sigf(zo)*tanhf(c);
    cst[idx] = c;
    unsigned short hb = f2bf(h);
    hoh[idx] = hb;
    hol[idx] = f2bf(h - bf2f(hb));
  }
}

// ------------- decoder layer 1 + fused logits -------------------------------
// K=1024 = [x(=h0out); h1prev]. Per iteration process BOTH streams (ks and
// ks+16) — two independent load/MFMA chains for free ILP, no manual staging.
__global__ void __launch_bounds__(512,2) dec_l1_mfma(
    const unsigned short* __restrict__ xh, const unsigned short* __restrict__ xl,
    const unsigned short* __restrict__ wh, const unsigned short* __restrict__ wl,
    const float* __restrict__ bias,
    const unsigned short* __restrict__ hih, const unsigned short* __restrict__ hil,
    unsigned short* __restrict__ hoh, unsigned short* __restrict__ hol,
    float* __restrict__ cst,
    const float* __restrict__ outW,
    float* __restrict__ out, int t)
{
  const int bid = blockIdx.x;
  const int by = bid & 15;
  const int bx = bid >> 4;
  const int e0 = bx * 64;
  const int lane = threadIdx.x & 63;
  const int w = threadIdx.x >> 6;
  const int wm = w & 3, wu = w >> 2;
  const int ut = by*2 + wu;
  const int lo16 = lane & 15, kgrp = lane >> 4;
  const int arow = e0 + wm*16 + lo16;
  const int u = ut*16 + lo16;
  const int r0 = e0 + wm*16 + kgrp*4;

  const unsigned short* pxh = xh  + (size_t)arow*512 + kgrp*8;
  const unsigned short* pxl = xl  + (size_t)arow*512 + kgrp*8;
  const unsigned short* pah = hih + (size_t)arow*512 + kgrp*8;
  const unsigned short* pal = hil + (size_t)arow*512 + kgrp*8;
  const unsigned short* pb[8];
  #pragma unroll
  for (int q=0;q<4;q++){
    size_t off = ((size_t)(q*32+ut)*32*64 + lane)*8;   // KT=32
    pb[q]   = wh + off;
    pb[q+4] = wl + off;
  }
  const f32x4 z4 = {0.f,0.f,0.f,0.f};
  f32x4 aHH[4]={z4,z4,z4,z4}, aLH[4]={z4,z4,z4,z4}, aHL[4]={z4,z4,z4,z4};

  #pragma unroll 2
  for (int ks=0; ks<16; ks++){
    // stream 1: x-part (kt = ks)
    bf16x8 axh = *(const bf16x8*)(pxh + (size_t)ks*32);
    bf16x8 axl = *(const bf16x8*)(pxl + (size_t)ks*32);
    // stream 2: h-part (kt = ks+16), fully independent pointers
    bf16x8 ahh = *(const bf16x8*)(pah + (size_t)ks*32);
    bf16x8 ahl = *(const bf16x8*)(pal + (size_t)ks*32);
    #pragma unroll
    for (int q=0;q<4;q++){
      bf16x8 bxh = *(const bf16x8*)(pb[q]   + (size_t)ks*512);
      bf16x8 bxl = *(const bf16x8*)(pb[q+4] + (size_t)ks*512);
      aHH[q] = __builtin_amdgcn_mfma_f32_16x16x32_bf16(axh, bxh, aHH[q], 0,0,0);
      aLH[q] = __builtin_amdgcn_mfma_f32_16x16x32_bf16(axl, bxh, aLH[q], 0,0,0);
      aHL[q] = __builtin_amdgcn_mfma_f32_16x16x32_bf16(axh, bxl, aHL[q], 0,0,0);
    }
    #pragma unroll
    for (int q=0;q<4;q++){
      bf16x8 bhh = *(const bf16x8*)(pb[q]   + (size_t)(ks+16)*512);
      bf16x8 bhl = *(const bf16x8*)(pb[q+4] + (size_t)(ks+16)*512);
      aHH[q] = __builtin_amdgcn_mfma_f32_16x16x32_bf16(ahh, bhh, aHH[q], 0,0,0);
      aLH[q] = __builtin_amdgcn_mfma_f32_16x16x32_bf16(ahl, bhh, aLH[q], 0,0,0);
      aHL[q] = __builtin_amdgcn_mfma_f32_16x16x32_bf16(ahh, bhl, aHL[q], 0,0,0);
    }
  }

  const float b0 = bias[u], b1 = bias[512+u], b2 = bias[1024+u], b3 = bias[1536+u];
  float ow[5];
  #pragma unroll
  for (int v=0;v<5;v++) ow[v] = outW[v*512 + u];

  float hv[4];
  #pragma unroll
  for (int r=0;r<4;r++){
    const int e = r0 + r;
    float zi = aHH[0][r]+aLH[0][r]+aHL[0][r] + b0;
    float zf = aHH[1][r]+aLH[1][r]+aHL[1][r] + b1;
    float zg = aHH[2][r]+aLH[2][r]+aHL[2][r] + b2;
    float zo = aHH[3][r]+aLH[3][r]+aHL[3][r] + b3;
    const size_t idx = (size_t)e*512 + u;
    float c = sigf(zf)*cst[idx] + sigf(zi)*tanhf(zg);
    float h = sigf(zo)*tanhf(c);
    cst[idx] = c;
    hv[r] = h;
    unsigned short hb = f2bf(h);
    hoh[idx] = hb;
    hol[idx] = f2bf(h - bf2f(hb));
  }
  // partial logits: reduce over 16 lanes (units of this tile), atomicAdd
  #pragma unroll
  for (int r=0;r<4;r++){
    #pragma unroll
    for (int v=0;v<5;v++){
      float psum = hv[r]*ow[v];
      psum += __shfl_xor(psum, 1);
      psum += __shfl_xor(psum, 2);
      psum += __shfl_xor(psum, 4);
      psum += __shfl_xor(psum, 8);
      if (lo16 == 0)
        atomicAdd(out + ((size_t)(r0+r)*TDEC + t)*5 + v, psum);
    }
  }
}

extern "C" void kernel_launch(void* const* d_in, const int* in_sizes, int n_in,
                              void* d_out, int out_size, void* d_ws, size_t ws_size,
                              hipStream_t stream){
  (void)in_sizes; (void)n_in; (void)out_size;
  const int*   leftc    = (const int*)d_in[0];
  const int*   rightc   = (const int*)d_in[1];
  const float* emb      = (const float*)d_in[3];
  const float* ctx0_Wih = (const float*)d_in[4];
  const float* ctx0_Whh = (const float*)d_in[5];
  const float* ctx0_b   = (const float*)d_in[6];
  const float* ctx1_Wih = (const float*)d_in[7];
  const float* ctx1_Whh = (const float*)d_in[8];
  const float* ctx1_b   = (const float*)d_in[9];
  const float* gen0_Wih = (const float*)d_in[10];
  const float* gen0_Whh = (const float*)d_in[11];
  const float* gen0_b   = (const float*)d_in[12];
  const float* gen1_Wih = (const float*)d_in[13];
  const float* gen1_Whh = (const float*)d_in[14];
  const float* gen1_b   = (const float*)d_in[15];
  const float* out_W    = (const float*)d_in[16];
  const float* out_b    = (const float*)d_in[17];
  float* out = (float*)d_out;

  char* p = (char*)d_ws;
  auto carve = [&](size_t nfloats)->float*{
    float* r = (float*)p;
    p += ((nfloats*sizeof(float) + 255) & ~(size_t)255);
    return r;
  };
  auto carveu = [&](size_t nush)->unsigned short*{
    return (unsigned short*)carve((nush + 1)/2);
  };
  float* ectx0  = carve(2*5*1024);
  float* egen0  = carve(5*2048);
  float* leftF  = carve((size_t)BATCH*HG);
  float* rightF = carve((size_t)BATCH*HG);
  float* c0s    = carve((size_t)BATCH*HG);
  float* c1s    = carve((size_t)BATCH*HG);
  unsigned short* c0pkh = carveu((size_t)2*1024*256);
  unsigned short* c0pkl = carveu((size_t)2*1024*256);
  unsigned short* c1pkh = carveu((size_t)2*1024*768);
  unsigned short* c1pkl = carveu((size_t)2*1024*768);
  unsigned short* pk0h = carveu((size_t)2048*512);
  unsigned short* pk0l = carveu((size_t)2048*512);
  unsigned short* pk1h = carveu((size_t)2048*1024);
  unsigned short* pk1l = carveu((size_t)2048*1024);
  unsigned short* h0ha = carveu((size_t)BATCH*HG);
  unsigned short* h0la = carveu((size_t)BATCH*HG);
  unsigned short* h0hb = carveu((size_t)BATCH*HG);
  unsigned short* h0lb = carveu((size_t)BATCH*HG);
  unsigned short* h1ha = carveu((size_t)BATCH*HG);
  unsigned short* h1la = carveu((size_t)BATCH*HG);
  unsigned short* h1hb = carveu((size_t)BATCH*HG);
  unsigned short* h1lb = carveu((size_t)BATCH*HG);
  unsigned short* y0h = carveu((size_t)L_SEQ*BATCH*512);   // 105 MB
  unsigned short* y0l = carveu((size_t)L_SEQ*BATCH*512);   // 105 MB
  if ((size_t)(p - (char*)d_ws) > ws_size) return;  // insufficient workspace -> loud fail

  // weight packs (fragment-linear bf16 hi/lo)
  for (int d=0; d<2; d++){
    pack_w<<<128, 256, 0, stream>>>(ctx0_Whh + (size_t)d*1024*256, 1024, 256, 8, 0,
                                    c0pkh + (size_t)d*262144, c0pkl + (size_t)d*262144);
    pack_w<<<256, 256, 0, stream>>>(ctx1_Wih + (size_t)d*1024*512, 1024, 512, 24, 0,
                                    c1pkh + (size_t)d*786432, c1pkl + (size_t)d*786432);
    pack_w<<<128, 256, 0, stream>>>(ctx1_Whh + (size_t)d*1024*256, 1024, 256, 24, 16,
                                    c1pkh + (size_t)d*786432, c1pkl + (size_t)d*786432);
  }
  pack_w<<<512, 256, 0, stream>>>(gen0_Whh, 2048, 512, 16,  0, pk0h, pk0l);
  pack_w<<<512, 256, 0, stream>>>(gen1_Wih, 2048, 512, 32,  0, pk1h, pk1l);
  pack_w<<<512, 256, 0, stream>>>(gen1_Whh, 2048, 512, 32, 16, pk1h, pk1l);

  embprep<<<(20480+255)/256, 256, 0, stream>>>(emb, ctx0_Wih, ctx0_b,
                                               gen0_Wih, gen0_b, ectx0, egen0);
  prefill_out<<<(BATCH*TDEC*5+255)/256, 256, 0, stream>>>(out, out_b);

  // left encode (finals at t=99), then right (finals at t=0); y0 reused
  ctx_l0_mfma<<<128, 512, 0, stream>>>(leftc, ectx0, c0pkh, c0pkl, y0h, y0l);
  ctx_l1_mfma<<<128, 512, 0, stream>>>(y0h, y0l, c1pkh, c1pkl, ctx1_b, leftF, L_SEQ-1);
  ctx_l0_mfma<<<128, 512, 0, stream>>>(rightc, ectx0, c0pkh, c0pkl, y0h, y0l);
  ctx_l1_mfma<<<128, 512, 0, stream>>>(y0h, y0l, c1pkh, c1pkl, ctx1_b, rightF, 0);

  combine_init2<<<(BATCH*HG+255)/256, 256, 0, stream>>>(leftF, rightF,
                                                        h0ha, h0la, h1ha, h1la,
                                                        c0s, c1s);

  for (int t=0;t<TDEC;t++){
    unsigned short* h0ih = (t&1)? h0hb : h0ha;
    unsigned short* h0il = (t&1)? h0lb : h0la;
    unsigned short* h0oh = (t&1)? h0ha : h0hb;
    unsigned short* h0ol = (t&1)? h0la : h0lb;
    unsigned short* h1ih = (t&1)? h1hb : h1ha;
    unsigned short* h1il = (t&1)? h1lb : h1la;
    unsigned short* h1oh = (t&1)? h1ha : h1hb;
    unsigned short* h1ol = (t&1)? h1la : h1lb;
    dec_l0_mfma<<<256, 512, 0, stream>>>(out, egen0, pk0h, pk0l,
                                         h0ih, h0il, h0oh, h0ol, c0s, t);
    dec_l1_mfma<<<256, 512, 0, stream>>>(h0oh, h0ol, pk1h, pk1l, gen1_b,
                                         h1ih, h1il, h1oh, h1ol, c1s,
                                         out_W, out, t);
  }
}

// Round 6
// 31419.559 us; speedup vs baseline: 1.4534x; 1.0092x over previous
//
#include <hip/hip_runtime.h>

// LSTMGapFiller R7: kill the R5/R6 atomic storm. Logits+argmax move INTO
// dec_l0 as block-local redundant compute (each 16-lane group computes its 4
// rows' 5 logits from h1prev + outW, argmax feeds epilogue directly; by==0
// blocks store step t-1 logits as plain stores). dec_l1 back to pure LSTM (no
// atomics, no outW). Trailing dec_outF writes t=255 logits. 2 launches/step,
// zero atomics, no tok buffer. MFMA loops bit-identical to R6 (isolates the
// storm-removal delta). Context stack unchanged (R3).

#define L_SEQ 100
#define BATCH 1024
#define HCTX 256
#define HG 512
#define TDEC 256

typedef __attribute__((ext_vector_type(8))) short bf16x8;
typedef __attribute__((ext_vector_type(4))) float f32x4;

__device__ __forceinline__ float sigf(float x){ return 1.0f/(1.0f+expf(-x)); }
__device__ __forceinline__ unsigned short f2bf(float x){
  unsigned int u = __float_as_uint(x);
  return (unsigned short)((u + 0x7fffu + ((u>>16)&1u)) >> 16);   // RNE
}
__device__ __forceinline__ float bf2f(unsigned short h){
  return __uint_as_float(((unsigned int)h)<<16);
}

// Pack W[G][K] (fp32, row-major) into MFMA-fragment-linear bf16 hi/lo.
__global__ void pack_w(const float* __restrict__ W, int G, int K, int KTtot, int kt0,
                       unsigned short* __restrict__ hi, unsigned short* __restrict__ lo){
  int idx = blockIdx.x*blockDim.x + threadIdx.x;
  int kt_n = K/32;
  int total = (G/16)*kt_n*64;
  if (idx >= total) return;
  int lane = idx & 63;
  int ktl = (idx>>6) % kt_n;
  int gt  = (idx>>6) / kt_n;
  int g = gt*16 + (lane & 15);
  int k = ktl*32 + (lane>>4)*8;
  const float* src = W + (size_t)g*K + k;
  size_t dst = (((size_t)gt*KTtot + (kt0 + ktl))*64 + lane)*8;
  #pragma unroll
  for (int j=0;j<8;j++){
    float x = src[j];
    unsigned short h = f2bf(x);
    hi[dst+j] = h;
    lo[dst+j] = f2bf(x - bf2f(h));
  }
}

// embedding projections (vocab=5)
__global__ void embprep(const float* __restrict__ emb,
                        const float* __restrict__ c0Wih, const float* __restrict__ c0b,
                        const float* __restrict__ g0Wih, const float* __restrict__ g0b,
                        float* __restrict__ ectx0, float* __restrict__ egen0){
  int idx = blockIdx.x*blockDim.x + threadIdx.x;
  if (idx < 2*5*1024){
    int d = idx / 5120;
    int v = (idx / 1024) % 5;
    int j = idx % 1024;
    const float* w = c0Wih + ((size_t)d*1024 + j)*64;
    const float* e = emb + v*64;
    float s = c0b[d*1024 + j];
    #pragma unroll
    for (int k=0;k<64;k++) s += e[k]*w[k];
    ectx0[idx] = s;
  } else if (idx < 2*5*1024 + 5*2048){
    int i2 = idx - 10240;
    int v = i2 / 2048;
    int j = i2 % 2048;
    const float* w = g0Wih + (size_t)j*64;
    const float* e = emb + v*64;
    float s = g0b[j];
    #pragma unroll
    for (int k=0;k<64;k++) s += e[k]*w[k];
    egen0[i2] = s;
  }
}

// ---------------- context layer 0 (MFMA) ---------------- (unchanged R3)
__global__ void __launch_bounds__(512,1) ctx_l0_mfma(
    const int* __restrict__ toks,
    const float* __restrict__ ectx0,
    const unsigned short* __restrict__ wh, const unsigned short* __restrict__ wl,
    unsigned short* __restrict__ y0h, unsigned short* __restrict__ y0l)
{
  const int id  = blockIdx.x;
  const int dir = (id >> 2) & 1;
  const int bx  = ((id >> 3) << 2) | (id & 3);
  const int e0  = bx * 16;
  const int lane = threadIdx.x & 63;
  const int w    = threadIdx.x >> 6;
  const int lo16 = lane & 15, kgrp = lane >> 4;

  __shared__ unsigned short hsh[16*256];
  __shared__ unsigned short hsl[16*256];
  __shared__ float cs[16*256];
  for (int i=threadIdx.x;i<16*256;i+=512){ hsh[i]=0; hsl[i]=0; cs[i]=0.f; }
  __syncthreads();

  const unsigned short* pbh[4][2];
  const unsigned short* pbl[4][2];
  #pragma unroll
  for (int g=0;g<4;g++){
    #pragma unroll
    for (int st=0;st<2;st++){
      int ct = g*16 + w*2 + st;
      size_t off = (size_t)dir*1024*256 + ((size_t)(ct*8)*64 + lane)*8;
      pbh[g][st] = wh + off; pbl[g][st] = wl + off;
    }
  }
  const unsigned aoff0 = (unsigned)(lo16*512 + kgrp*16);
  const unsigned axor  = ((unsigned)(lo16 & 7)) << 4;

  for (int s=0;s<L_SEQ;s++){
    const int t = dir ? (L_SEQ-1-s) : s;
    f32x4 zero = {0.f,0.f,0.f,0.f};
    f32x4 acc[4][2];
    #pragma unroll
    for (int g=0;g<4;g++){
      #pragma unroll
      for (int st=0;st<2;st++) acc[g][st] = zero;
    }
    #pragma unroll 2
    for (int kt=0;kt<8;kt++){
      unsigned ao = (aoff0 + kt*64) ^ axor;
      bf16x8 ah = *(const bf16x8*)((const char*)hsh + ao);
      bf16x8 al = *(const bf16x8*)((const char*)hsl + ao);
      #pragma unroll
      for (int g=0;g<4;g++){
        #pragma unroll
        for (int st=0;st<2;st++){
          bf16x8 bh = *(const bf16x8*)(pbh[g][st] + (size_t)kt*512);
          bf16x8 bl = *(const bf16x8*)(pbl[g][st] + (size_t)kt*512);
          acc[g][st] = __builtin_amdgcn_mfma_f32_16x16x32_bf16(ah,bh,acc[g][st],0,0,0);
          acc[g][st] = __builtin_amdgcn_mfma_f32_16x16x32_bf16(al,bh,acc[g][st],0,0,0);
          acc[g][st] = __builtin_amdgcn_mfma_f32_16x16x32_bf16(ah,bl,acc[g][st],0,0,0);
        }
      }
    }
    __syncthreads();
    int tkr[4];
    #pragma unroll
    for (int r=0;r<4;r++) tkr[r] = toks[(e0 + kgrp*4 + r)*L_SEQ + t];
    #pragma unroll
    for (int st=0;st<2;st++){
      const int unit = w*32 + st*16 + lo16;
      #pragma unroll
      for (int r=0;r<4;r++){
        const int row = kgrp*4 + r;
        const int e = e0 + row;
        const float* ep = ectx0 + ((size_t)(dir*5 + tkr[r]))*1024 + unit;
        float zi = acc[0][st][r] + ep[0];
        float zf = acc[1][st][r] + ep[256];
        float zg = acc[2][st][r] + ep[512];
        float zo = acc[3][st][r] + ep[768];
        int ci = row*256 + unit;
        float c = sigf(zf)*cs[ci] + sigf(zi)*tanhf(zg);
        float h = sigf(zo)*tanhf(c);
        cs[ci] = c;
        unsigned short hb = f2bf(h), lb = f2bf(h - bf2f(hb));
        unsigned hoff = ((unsigned)(row*512 + unit*2)) ^ (((unsigned)(row & 7)) << 4);
        *(unsigned short*)((char*)hsh + hoff) = hb;
        *(unsigned short*)((char*)hsl + hoff) = lb;
        size_t yo = ((size_t)t*BATCH + e)*512 + dir*256 + unit;
        y0h[yo] = hb; y0l[yo] = lb;
      }
    }
    __syncthreads();
  }
}

// ---------------- context layer 1 (MFMA) ---------------- (unchanged R3)
__global__ void __launch_bounds__(512,1) ctx_l1_mfma(
    const unsigned short* __restrict__ y0h, const unsigned short* __restrict__ y0l,
    const unsigned short* __restrict__ wh, const unsigned short* __restrict__ wl,
    const float* __restrict__ bias,
    float* __restrict__ finals, int t_store)
{
  const int id  = blockIdx.x;
  const int dir = (id >> 2) & 1;
  const int bx  = ((id >> 3) << 2) | (id & 3);
  const int e0  = bx * 16;
  const int lane = threadIdx.x & 63;
  const int w    = threadIdx.x >> 6;
  const int lo16 = lane & 15, kgrp = lane >> 4;

  __shared__ unsigned short xsh[16*512];
  __shared__ unsigned short xsl[16*512];
  __shared__ unsigned short hsh[16*256];
  __shared__ unsigned short hsl[16*256];
  __shared__ float cs[16*256];
  for (int i=threadIdx.x;i<16*256;i+=512){ hsh[i]=0; hsl[i]=0; cs[i]=0.f; }

  float bb[4][2];
  #pragma unroll
  for (int g=0;g<4;g++){
    #pragma unroll
    for (int st=0;st<2;st++)
      bb[g][st] = bias[dir*1024 + g*256 + w*32 + st*16 + lo16];
  }
  const unsigned short* pbh[4][2];
  const unsigned short* pbl[4][2];
  #pragma unroll
  for (int g=0;g<4;g++){
    #pragma unroll
    for (int st=0;st<2;st++){
      int ct = g*16 + w*2 + st;
      size_t off = (size_t)dir*1024*768 + ((size_t)(ct*24)*64 + lane)*8;
      pbh[g][st] = wh + off; pbl[g][st] = wl + off;
    }
  }
  const unsigned axor = ((unsigned)(lo16 & 7)) << 4;
  __syncthreads();

  for (int s=0;s<L_SEQ;s++){
    const int t = dir ? (L_SEQ-1-s) : s;
    #pragma unroll
    for (int cc=0; cc<2; cc++){
      int ci = threadIdx.x + cc*512;
      int row = ci >> 6, cr = ci & 63;
      const unsigned short* srcbase = y0h + ((size_t)t*BATCH + e0 + row)*512 + cr*8;
      const unsigned short* srcbasel = y0l + ((size_t)t*BATCH + e0 + row)*512 + cr*8;
      uint4 vh = *(const uint4*)srcbase;
      uint4 vl = *(const uint4*)srcbasel;
      unsigned xo = ((unsigned)(row*1024 + cr*16)) ^ (((unsigned)(row & 7)) << 4);
      *(uint4*)((char*)xsh + xo) = vh;
      *(uint4*)((char*)xsl + xo) = vl;
    }
    __syncthreads();
    f32x4 zero = {0.f,0.f,0.f,0.f};
    f32x4 acc[4][2];
    #pragma unroll
    for (int g=0;g<4;g++){
      #pragma unroll
      for (int st=0;st<2;st++) acc[g][st] = zero;
    }
    #pragma unroll 2
    for (int kt=0;kt<16;kt++){
      unsigned ao = ((unsigned)(lo16*1024 + kt*64 + kgrp*16)) ^ axor;
      bf16x8 ah = *(const bf16x8*)((const char*)xsh + ao);
      bf16x8 al = *(const bf16x8*)((const char*)xsl + ao);
      #pragma unroll
      for (int g=0;g<4;g++){
        #pragma unroll
        for (int st=0;st<2;st++){
          bf16x8 bh = *(const bf16x8*)(pbh[g][st] + (size_t)kt*512);
          bf16x8 bl = *(const bf16x8*)(pbl[g][st] + (size_t)kt*512);
          acc[g][st] = __builtin_amdgcn_mfma_f32_16x16x32_bf16(ah,bh,acc[g][st],0,0,0);
          acc[g][st] = __builtin_amdgcn_mfma_f32_16x16x32_bf16(al,bh,acc[g][st],0,0,0);
          acc[g][st] = __builtin_amdgcn_mfma_f32_16x16x32_bf16(ah,bl,acc[g][st],0,0,0);
        }
      }
    }
    #pragma unroll 2
    for (int kt=16;kt<24;kt++){
      unsigned ao = ((unsigned)(lo16*512 + (kt-16)*64 + kgrp*16)) ^ axor;
      bf16x8 ah = *(const bf16x8*)((const char*)hsh + ao);
      bf16x8 al = *(const bf16x8*)((const char*)hsl + ao);
      #pragma unroll
      for (int g=0;g<4;g++){
        #pragma unroll
        for (int st=0;st<2;st++){
          bf16x8 bh = *(const bf16x8*)(pbh[g][st] + (size_t)kt*512);
          bf16x8 bl = *(const bf16x8*)(pbl[g][st] + (size_t)kt*512);
          acc[g][st] = __builtin_amdgcn_mfma_f32_16x16x32_bf16(ah,bh,acc[g][st],0,0,0);
          acc[g][st] = __builtin_amdgcn_mfma_f32_16x16x32_bf16(al,bh,acc[g][st],0,0,0);
          acc[g][st] = __builtin_amdgcn_mfma_f32_16x16x32_bf16(ah,bl,acc[g][st],0,0,0);
        }
      }
    }
    __syncthreads();
    #pragma unroll
    for (int st=0;st<2;st++){
      const int unit = w*32 + st*16 + lo16;
      #pragma unroll
      for (int r=0;r<4;r++){
        const int row = kgrp*4 + r;
        float zi = acc[0][st][r] + bb[0][st];
        float zf = acc[1][st][r] + bb[1][st];
        float zg = acc[2][st][r] + bb[2][st];
        float zo = acc[3][st][r] + bb[3][st];
        int ci = row*256 + unit;
        float c = sigf(zf)*cs[ci] + sigf(zi)*tanhf(zg);
        float h = sigf(zo)*tanhf(c);
        cs[ci] = c;
        unsigned short hb = f2bf(h), lb = f2bf(h - bf2f(hb));
        unsigned hoff = ((unsigned)(row*512 + unit*2)) ^ (((unsigned)(row & 7)) << 4);
        *(unsigned short*)((char*)hsh + hoff) = hb;
        *(unsigned short*)((char*)hsl + hoff) = lb;
        if (t == t_store)
          finals[(size_t)(e0 + row)*512 + dir*256 + unit] = h;
      }
    }
    __syncthreads();
  }
}

__global__ void combine_init2(const float* __restrict__ lf, const float* __restrict__ rf,
                              unsigned short* __restrict__ h0h, unsigned short* __restrict__ h0l,
                              unsigned short* __restrict__ h1h, unsigned short* __restrict__ h1l,
                              float* __restrict__ c0, float* __restrict__ c1){
  int i = blockIdx.x*blockDim.x + threadIdx.x;
  if (i < BATCH*HG){
    float v = 0.5f*(lf[i]+rf[i]);
    unsigned short h = f2bf(v);
    unsigned short l = f2bf(v - bf2f(h));
    h0h[i]=h; h0l[i]=l; h1h[i]=h; h1l[i]=l;
    c0[i]=0.f; c1[i]=0.f;
  }
}

// ------------- decoder layer 0 (MFMA + block-local logits/argmax) -----------
// 256 blocks x 512 thr. by=bid&15 (weight slice); bx=bid>>4 (rows e0..e0+63).
// Logits of step t-1 computed redundantly per 16-lane group from h1prev+outW
// (no atomics, no cross-block reduce); argmax feeds the LSTM epilogue; by==0
// blocks store logits to out[.., t-1].
__global__ void __launch_bounds__(512,2) dec_l0_mfma(
    const float* __restrict__ egen0,
    const unsigned short* __restrict__ wh, const unsigned short* __restrict__ wl,
    const unsigned short* __restrict__ hih, const unsigned short* __restrict__ hil,
    const unsigned short* __restrict__ h1ih, const unsigned short* __restrict__ h1il,
    unsigned short* __restrict__ hoh, unsigned short* __restrict__ hol,
    float* __restrict__ cst,
    const float* __restrict__ outW, const float* __restrict__ outb,
    float* __restrict__ out, int t)
{
  const int bid = blockIdx.x;
  const int by = bid & 15;
  const int bx = bid >> 4;
  const int e0 = bx * 64;
  const int lane = threadIdx.x & 63;
  const int w = threadIdx.x >> 6;
  const int wm = w & 3, wu = w >> 2;
  const int ut = by*2 + wu;
  const int lo16 = lane & 15, kgrp = lane >> 4;
  const int arow = e0 + wm*16 + lo16;
  const int u = ut*16 + lo16;
  const int r0 = e0 + wm*16 + kgrp*4;

  const unsigned short* pah = hih + (size_t)arow*512 + kgrp*8;
  const unsigned short* pal = hil + (size_t)arow*512 + kgrp*8;
  const unsigned short* pb[8];
  #pragma unroll
  for (int q=0;q<4;q++){
    size_t off = ((size_t)(q*32+ut)*16*64 + lane)*8;   // KT=16
    pb[q]   = wh + off;
    pb[q+4] = wl + off;
  }
  const f32x4 z4 = {0.f,0.f,0.f,0.f};
  f32x4 aHH[4]={z4,z4,z4,z4}, aLH[4]={z4,z4,z4,z4}, aHL[4]={z4,z4,z4,z4};

  #pragma unroll 2
  for (int ks=0; ks<16; ks++){
    bf16x8 ah = *(const bf16x8*)(pah + (size_t)ks*32);
    bf16x8 al = *(const bf16x8*)(pal + (size_t)ks*32);
    #pragma unroll
    for (int q=0;q<4;q++){
      bf16x8 bh = *(const bf16x8*)(pb[q]   + (size_t)ks*512);
      bf16x8 bl = *(const bf16x8*)(pb[q+4] + (size_t)ks*512);
      aHH[q] = __builtin_amdgcn_mfma_f32_16x16x32_bf16(ah, bh, aHH[q], 0,0,0);
      aLH[q] = __builtin_amdgcn_mfma_f32_16x16x32_bf16(al, bh, aLH[q], 0,0,0);
      aHL[q] = __builtin_amdgcn_mfma_f32_16x16x32_bf16(ah, bl, aHL[q], 0,0,0);
    }
  }

  // ---- logits of step t-1 for rows r0..r0+3, per 16-lane group ----
  int tkr[4] = {0,0,0,0};
  if (t > 0){
    float acc5[4][5];
    #pragma unroll
    for (int r=0;r<4;r++){
      #pragma unroll
      for (int v=0;v<5;v++) acc5[r][v]=0.f;
    }
    #pragma unroll
    for (int j=0;j<4;j++){
      const int ub = lo16*32 + j*8;          // 8 consecutive units per chunk
      f32x4 w0[5], w1[5];
      #pragma unroll
      for (int v=0;v<5;v++){
        const float* wp = outW + v*512 + ub;
        w0[v] = *(const f32x4*)(wp);
        w1[v] = *(const f32x4*)(wp+4);
      }
      #pragma unroll
      for (int r=0;r<4;r++){
        const unsigned short* hh = h1ih + (size_t)(r0+r)*512 + ub;
        const unsigned short* hl = h1il + (size_t)(r0+r)*512 + ub;
        bf16x8 vh = *(const bf16x8*)hh;
        bf16x8 vl = *(const bf16x8*)hl;
        #pragma unroll
        for (int m=0;m<4;m++){
          float hv = bf2f((unsigned short)vh[m]) + bf2f((unsigned short)vl[m]);
          #pragma unroll
          for (int v=0;v<5;v++) acc5[r][v] += hv * w0[v][m];
        }
        #pragma unroll
        for (int m=0;m<4;m++){
          float hv = bf2f((unsigned short)vh[m+4]) + bf2f((unsigned short)vl[m+4]);
          #pragma unroll
          for (int v=0;v<5;v++) acc5[r][v] += hv * w1[v][m];
        }
      }
    }
    #pragma unroll
    for (int r=0;r<4;r++){
      #pragma unroll
      for (int v=0;v<5;v++){
        float s = acc5[r][v];
        s += __shfl_xor(s, 1);
        s += __shfl_xor(s, 2);
        s += __shfl_xor(s, 4);
        s += __shfl_xor(s, 8);
        acc5[r][v] = s + outb[v];
      }
      float best = acc5[r][0]; int tk = 0;
      if (acc5[r][1] > best){ best = acc5[r][1]; tk = 1; }
      if (acc5[r][2] > best){ best = acc5[r][2]; tk = 2; }
      if (acc5[r][3] > best){ best = acc5[r][3]; tk = 3; }
      if (acc5[r][4] > best){ best = acc5[r][4]; tk = 4; }
      tkr[r] = tk;
    }
    if (by == 0 && wu == 0 && lo16 == 0){
      #pragma unroll
      for (int r=0;r<4;r++){
        float* op = out + ((size_t)(r0+r)*TDEC + (t-1))*5;
        #pragma unroll
        for (int v=0;v<5;v++) op[v] = acc5[r][v];
      }
    }
  }

  #pragma unroll
  for (int r=0;r<4;r++){
    const int e = r0 + r;
    const float* ep = egen0 + (size_t)tkr[r]*2048 + u;
    float zi = aHH[0][r]+aLH[0][r]+aHL[0][r] + ep[0];
    float zf = aHH[1][r]+aLH[1][r]+aHL[1][r] + ep[512];
    float zg = aHH[2][r]+aLH[2][r]+aHL[2][r] + ep[1024];
    float zo = aHH[3][r]+aLH[3][r]+aHL[3][r] + ep[1536];
    const size_t idx = (size_t)e*512 + u;
    float c = sigf(zf)*cst[idx] + sigf(zi)*tanhf(zg);
    float h = sigf(zo)*tanhf(c);
    cst[idx] = c;
    unsigned short hb = f2bf(h);
    hoh[idx] = hb;
    hol[idx] = f2bf(h - bf2f(hb));
  }
}

// ------------- decoder layer 1 (pure LSTM, no logits) -----------------------
// K=1024 = [x(=h0out); h1prev], dual independent streams per iter (ks, ks+16).
__global__ void __launch_bounds__(512,2) dec_l1_mfma(
    const unsigned short* __restrict__ xh, const unsigned short* __restrict__ xl,
    const unsigned short* __restrict__ wh, const unsigned short* __restrict__ wl,
    const float* __restrict__ bias,
    const unsigned short* __restrict__ hih, const unsigned short* __restrict__ hil,
    unsigned short* __restrict__ hoh, unsigned short* __restrict__ hol,
    float* __restrict__ cst)
{
  const int bid = blockIdx.x;
  const int by = bid & 15;
  const int bx = bid >> 4;
  const int e0 = bx * 64;
  const int lane = threadIdx.x & 63;
  const int w = threadIdx.x >> 6;
  const int wm = w & 3, wu = w >> 2;
  const int ut = by*2 + wu;
  const int lo16 = lane & 15, kgrp = lane >> 4;
  const int arow = e0 + wm*16 + lo16;
  const int u = ut*16 + lo16;
  const int r0 = e0 + wm*16 + kgrp*4;

  const unsigned short* pxh = xh  + (size_t)arow*512 + kgrp*8;
  const unsigned short* pxl = xl  + (size_t)arow*512 + kgrp*8;
  const unsigned short* pah = hih + (size_t)arow*512 + kgrp*8;
  const unsigned short* pal = hil + (size_t)arow*512 + kgrp*8;
  const unsigned short* pb[8];
  #pragma unroll
  for (int q=0;q<4;q++){
    size_t off = ((size_t)(q*32+ut)*32*64 + lane)*8;   // KT=32
    pb[q]   = wh + off;
    pb[q+4] = wl + off;
  }
  const f32x4 z4 = {0.f,0.f,0.f,0.f};
  f32x4 aHH[4]={z4,z4,z4,z4}, aLH[4]={z4,z4,z4,z4}, aHL[4]={z4,z4,z4,z4};

  #pragma unroll 2
  for (int ks=0; ks<16; ks++){
    bf16x8 axh = *(const bf16x8*)(pxh + (size_t)ks*32);
    bf16x8 axl = *(const bf16x8*)(pxl + (size_t)ks*32);
    bf16x8 ahh = *(const bf16x8*)(pah + (size_t)ks*32);
    bf16x8 ahl = *(const bf16x8*)(pal + (size_t)ks*32);
    #pragma unroll
    for (int q=0;q<4;q++){
      bf16x8 bxh = *(const bf16x8*)(pb[q]   + (size_t)ks*512);
      bf16x8 bxl = *(const bf16x8*)(pb[q+4] + (size_t)ks*512);
      aHH[q] = __builtin_amdgcn_mfma_f32_16x16x32_bf16(axh, bxh, aHH[q], 0,0,0);
      aLH[q] = __builtin_amdgcn_mfma_f32_16x16x32_bf16(axl, bxh, aLH[q], 0,0,0);
      aHL[q] = __builtin_amdgcn_mfma_f32_16x16x32_bf16(axh, bxl, aHL[q], 0,0,0);
    }
    #pragma unroll
    for (int q=0;q<4;q++){
      bf16x8 bhh = *(const bf16x8*)(pb[q]   + (size_t)(ks+16)*512);
      bf16x8 bhl = *(const bf16x8*)(pb[q+4] + (size_t)(ks+16)*512);
      aHH[q] = __builtin_amdgcn_mfma_f32_16x16x32_bf16(ahh, bhh, aHH[q], 0,0,0);
      aLH[q] = __builtin_amdgcn_mfma_f32_16x16x32_bf16(ahl, bhh, aLH[q], 0,0,0);
      aHL[q] = __builtin_amdgcn_mfma_f32_16x16x32_bf16(ahh, bhl, aHL[q], 0,0,0);
    }
  }

  const float b0 = bias[u], b1 = bias[512+u], b2 = bias[1024+u], b3 = bias[1536+u];
  #pragma unroll
  for (int r=0;r<4;r++){
    const int e = r0 + r;
    float zi = aHH[0][r]+aLH[0][r]+aHL[0][r] + b0;
    float zf = aHH[1][r]+aLH[1][r]+aHL[1][r] + b1;
    float zg = aHH[2][r]+aLH[2][r]+aHL[2][r] + b2;
    float zo = aHH[3][r]+aLH[3][r]+aHL[3][r] + b3;
    const size_t idx = (size_t)e*512 + u;
    float c = sigf(zf)*cst[idx] + sigf(zi)*tanhf(zg);
    float h = sigf(zo)*tanhf(c);
    cst[idx] = c;
    unsigned short hb = f2bf(h);
    hoh[idx] = hb;
    hol[idx] = f2bf(h - bf2f(hb));
  }
}

// final-step logits (t = TDEC-1): one wave per batch elem
__global__ void dec_outF(const unsigned short* __restrict__ h1h,
                         const unsigned short* __restrict__ h1l,
                         const float* __restrict__ outW,
                         const float* __restrict__ outb,
                         float* __restrict__ out){
  const int lane = threadIdx.x & 63;
  const int e = blockIdx.x*4 + (threadIdx.x >> 6);
  const unsigned short* hh = h1h + (size_t)e*512;
  const unsigned short* hl = h1l + (size_t)e*512;
  float s0=0,s1=0,s2=0,s3=0,s4=0;
  for (int k=lane;k<512;k+=64){
    float hv = bf2f(hh[k]) + bf2f(hl[k]);
    s0 += hv*outW[k];
    s1 += hv*outW[512+k];
    s2 += hv*outW[1024+k];
    s3 += hv*outW[1536+k];
    s4 += hv*outW[2048+k];
  }
  #pragma unroll
  for (int off=32; off>0; off>>=1){
    s0 += __shfl_down(s0, off);
    s1 += __shfl_down(s1, off);
    s2 += __shfl_down(s2, off);
    s3 += __shfl_down(s3, off);
    s4 += __shfl_down(s4, off);
  }
  if (lane==0){
    float* op = out + ((size_t)e*TDEC + (TDEC-1))*5;
    op[0]=s0+outb[0]; op[1]=s1+outb[1]; op[2]=s2+outb[2];
    op[3]=s3+outb[3]; op[4]=s4+outb[4];
  }
}

extern "C" void kernel_launch(void* const* d_in, const int* in_sizes, int n_in,
                              void* d_out, int out_size, void* d_ws, size_t ws_size,
                              hipStream_t stream){
  (void)in_sizes; (void)n_in; (void)out_size;
  const int*   leftc    = (const int*)d_in[0];
  const int*   rightc   = (const int*)d_in[1];
  const float* emb      = (const float*)d_in[3];
  const float* ctx0_Wih = (const float*)d_in[4];
  const float* ctx0_Whh = (const float*)d_in[5];
  const float* ctx0_b   = (const float*)d_in[6];
  const float* ctx1_Wih = (const float*)d_in[7];
  const float* ctx1_Whh = (const float*)d_in[8];
  const float* ctx1_b   = (const float*)d_in[9];
  const float* gen0_Wih = (const float*)d_in[10];
  const float* gen0_Whh = (const float*)d_in[11];
  const float* gen0_b   = (const float*)d_in[12];
  const float* gen1_Wih = (const float*)d_in[13];
  const float* gen1_Whh = (const float*)d_in[14];
  const float* gen1_b   = (const float*)d_in[15];
  const float* out_W    = (const float*)d_in[16];
  const float* out_b    = (const float*)d_in[17];
  float* out = (float*)d_out;

  char* p = (char*)d_ws;
  auto carve = [&](size_t nfloats)->float*{
    float* r = (float*)p;
    p += ((nfloats*sizeof(float) + 255) & ~(size_t)255);
    return r;
  };
  auto carveu = [&](size_t nush)->unsigned short*{
    return (unsigned short*)carve((nush + 1)/2);
  };
  float* ectx0  = carve(2*5*1024);
  float* egen0  = carve(5*2048);
  float* leftF  = carve((size_t)BATCH*HG);
  float* rightF = carve((size_t)BATCH*HG);
  float* c0s    = carve((size_t)BATCH*HG);
  float* c1s    = carve((size_t)BATCH*HG);
  unsigned short* c0pkh = carveu((size_t)2*1024*256);
  unsigned short* c0pkl = carveu((size_t)2*1024*256);
  unsigned short* c1pkh = carveu((size_t)2*1024*768);
  unsigned short* c1pkl = carveu((size_t)2*1024*768);
  unsigned short* pk0h = carveu((size_t)2048*512);
  unsigned short* pk0l = carveu((size_t)2048*512);
  unsigned short* pk1h = carveu((size_t)2048*1024);
  unsigned short* pk1l = carveu((size_t)2048*1024);
  unsigned short* h0ha = carveu((size_t)BATCH*HG);
  unsigned short* h0la = carveu((size_t)BATCH*HG);
  unsigned short* h0hb = carveu((size_t)BATCH*HG);
  unsigned short* h0lb = carveu((size_t)BATCH*HG);
  unsigned short* h1ha = carveu((size_t)BATCH*HG);
  unsigned short* h1la = carveu((size_t)BATCH*HG);
  unsigned short* h1hb = carveu((size_t)BATCH*HG);
  unsigned short* h1lb = carveu((size_t)BATCH*HG);
  unsigned short* y0h = carveu((size_t)L_SEQ*BATCH*512);   // 105 MB
  unsigned short* y0l = carveu((size_t)L_SEQ*BATCH*512);   // 105 MB
  if ((size_t)(p - (char*)d_ws) > ws_size) return;  // insufficient workspace -> loud fail

  // weight packs (fragment-linear bf16 hi/lo)
  for (int d=0; d<2; d++){
    pack_w<<<128, 256, 0, stream>>>(ctx0_Whh + (size_t)d*1024*256, 1024, 256, 8, 0,
                                    c0pkh + (size_t)d*262144, c0pkl + (size_t)d*262144);
    pack_w<<<256, 256, 0, stream>>>(ctx1_Wih + (size_t)d*1024*512, 1024, 512, 24, 0,
                                    c1pkh + (size_t)d*786432, c1pkl + (size_t)d*786432);
    pack_w<<<128, 256, 0, stream>>>(ctx1_Whh + (size_t)d*1024*256, 1024, 256, 24, 16,
                                    c1pkh + (size_t)d*786432, c1pkl + (size_t)d*786432);
  }
  pack_w<<<512, 256, 0, stream>>>(gen0_Whh, 2048, 512, 16,  0, pk0h, pk0l);
  pack_w<<<512, 256, 0, stream>>>(gen1_Wih, 2048, 512, 32,  0, pk1h, pk1l);
  pack_w<<<512, 256, 0, stream>>>(gen1_Whh, 2048, 512, 32, 16, pk1h, pk1l);

  embprep<<<(20480+255)/256, 256, 0, stream>>>(emb, ctx0_Wih, ctx0_b,
                                               gen0_Wih, gen0_b, ectx0, egen0);

  // left encode (finals at t=99), then right (finals at t=0); y0 reused
  ctx_l0_mfma<<<128, 512, 0, stream>>>(leftc, ectx0, c0pkh, c0pkl, y0h, y0l);
  ctx_l1_mfma<<<128, 512, 0, stream>>>(y0h, y0l, c1pkh, c1pkl, ctx1_b, leftF, L_SEQ-1);
  ctx_l0_mfma<<<128, 512, 0, stream>>>(rightc, ectx0, c0pkh, c0pkl, y0h, y0l);
  ctx_l1_mfma<<<128, 512, 0, stream>>>(y0h, y0l, c1pkh, c1pkl, ctx1_b, rightF, 0);

  combine_init2<<<(BATCH*HG+255)/256, 256, 0, stream>>>(leftF, rightF,
                                                        h0ha, h0la, h1ha, h1la,
                                                        c0s, c1s);

  for (int t=0;t<TDEC;t++){
    unsigned short* h0ih = (t&1)? h0hb : h0ha;
    unsigned short* h0il = (t&1)? h0lb : h0la;
    unsigned short* h0oh = (t&1)? h0ha : h0hb;
    unsigned short* h0ol = (t&1)? h0la : h0lb;
    unsigned short* h1ih = (t&1)? h1hb : h1ha;
    unsigned short* h1il = (t&1)? h1lb : h1la;
    unsigned short* h1oh = (t&1)? h1ha : h1hb;
    unsigned short* h1ol = (t&1)? h1la : h1lb;
    dec_l0_mfma<<<256, 512, 0, stream>>>(egen0, pk0h, pk0l,
                                         h0ih, h0il, h1ih, h1il,
                                         h0oh, h0ol, c0s,
                                         out_W, out_b, out, t);
    dec_l1_mfma<<<256, 512, 0, stream>>>(h0oh, h0ol, pk1h, pk1l, gen1_b,
                                         h1ih, h1il, h1oh, h1ol, c1s);
  }
  // t = TDEC-1 logits (h1 final lives in the 'a' buffers after odd t=255)
  dec_outF<<<256, 256, 0, stream>>>(h1ha, h1la, out_W, out_b, out);
}

// Round 7
// 28058.313 us; speedup vs baseline: 1.6275x; 1.1198x over previous
//
#include <hip/hip_runtime.h>

// LSTMGapFiller R8: despill the decoder. R6/R7's dual-stream dec_l1 kept ~24
// live bf16x8 fragments + 48 acc VGPRs under a 128-VGPR cap (launch_bounds
// (512,2)) -> scratch spills in the hot loop (R4's sequential form measured
// 104 VGPR, no spill). Fix: (a) dec_l1 back to sequential two K-loops with the
// 12 indep chains; (b) decoder launch_bounds -> (512,1): grid is exactly 256
// blocks on 256 CUs, so the 2-blocks/CU guarantee was unreachable and its
// VGPR cap pure cost. Everything else identical to R7 (no atomics, inline
// logits/argmax in dec_l0, dec_outF tail, R3 context stack).

#define L_SEQ 100
#define BATCH 1024
#define HCTX 256
#define HG 512
#define TDEC 256

typedef __attribute__((ext_vector_type(8))) short bf16x8;
typedef __attribute__((ext_vector_type(4))) float f32x4;

__device__ __forceinline__ float sigf(float x){ return 1.0f/(1.0f+expf(-x)); }
__device__ __forceinline__ unsigned short f2bf(float x){
  unsigned int u = __float_as_uint(x);
  return (unsigned short)((u + 0x7fffu + ((u>>16)&1u)) >> 16);   // RNE
}
__device__ __forceinline__ float bf2f(unsigned short h){
  return __uint_as_float(((unsigned int)h)<<16);
}

// Pack W[G][K] (fp32, row-major) into MFMA-fragment-linear bf16 hi/lo.
__global__ void pack_w(const float* __restrict__ W, int G, int K, int KTtot, int kt0,
                       unsigned short* __restrict__ hi, unsigned short* __restrict__ lo){
  int idx = blockIdx.x*blockDim.x + threadIdx.x;
  int kt_n = K/32;
  int total = (G/16)*kt_n*64;
  if (idx >= total) return;
  int lane = idx & 63;
  int ktl = (idx>>6) % kt_n;
  int gt  = (idx>>6) / kt_n;
  int g = gt*16 + (lane & 15);
  int k = ktl*32 + (lane>>4)*8;
  const float* src = W + (size_t)g*K + k;
  size_t dst = (((size_t)gt*KTtot + (kt0 + ktl))*64 + lane)*8;
  #pragma unroll
  for (int j=0;j<8;j++){
    float x = src[j];
    unsigned short h = f2bf(x);
    hi[dst+j] = h;
    lo[dst+j] = f2bf(x - bf2f(h));
  }
}

// embedding projections (vocab=5)
__global__ void embprep(const float* __restrict__ emb,
                        const float* __restrict__ c0Wih, const float* __restrict__ c0b,
                        const float* __restrict__ g0Wih, const float* __restrict__ g0b,
                        float* __restrict__ ectx0, float* __restrict__ egen0){
  int idx = blockIdx.x*blockDim.x + threadIdx.x;
  if (idx < 2*5*1024){
    int d = idx / 5120;
    int v = (idx / 1024) % 5;
    int j = idx % 1024;
    const float* w = c0Wih + ((size_t)d*1024 + j)*64;
    const float* e = emb + v*64;
    float s = c0b[d*1024 + j];
    #pragma unroll
    for (int k=0;k<64;k++) s += e[k]*w[k];
    ectx0[idx] = s;
  } else if (idx < 2*5*1024 + 5*2048){
    int i2 = idx - 10240;
    int v = i2 / 2048;
    int j = i2 % 2048;
    const float* w = g0Wih + (size_t)j*64;
    const float* e = emb + v*64;
    float s = g0b[j];
    #pragma unroll
    for (int k=0;k<64;k++) s += e[k]*w[k];
    egen0[i2] = s;
  }
}

// ---------------- context layer 0 (MFMA) ---------------- (unchanged R3)
__global__ void __launch_bounds__(512,1) ctx_l0_mfma(
    const int* __restrict__ toks,
    const float* __restrict__ ectx0,
    const unsigned short* __restrict__ wh, const unsigned short* __restrict__ wl,
    unsigned short* __restrict__ y0h, unsigned short* __restrict__ y0l)
{
  const int id  = blockIdx.x;
  const int dir = (id >> 2) & 1;
  const int bx  = ((id >> 3) << 2) | (id & 3);
  const int e0  = bx * 16;
  const int lane = threadIdx.x & 63;
  const int w    = threadIdx.x >> 6;
  const int lo16 = lane & 15, kgrp = lane >> 4;

  __shared__ unsigned short hsh[16*256];
  __shared__ unsigned short hsl[16*256];
  __shared__ float cs[16*256];
  for (int i=threadIdx.x;i<16*256;i+=512){ hsh[i]=0; hsl[i]=0; cs[i]=0.f; }
  __syncthreads();

  const unsigned short* pbh[4][2];
  const unsigned short* pbl[4][2];
  #pragma unroll
  for (int g=0;g<4;g++){
    #pragma unroll
    for (int st=0;st<2;st++){
      int ct = g*16 + w*2 + st;
      size_t off = (size_t)dir*1024*256 + ((size_t)(ct*8)*64 + lane)*8;
      pbh[g][st] = wh + off; pbl[g][st] = wl + off;
    }
  }
  const unsigned aoff0 = (unsigned)(lo16*512 + kgrp*16);
  const unsigned axor  = ((unsigned)(lo16 & 7)) << 4;

  for (int s=0;s<L_SEQ;s++){
    const int t = dir ? (L_SEQ-1-s) : s;
    f32x4 zero = {0.f,0.f,0.f,0.f};
    f32x4 acc[4][2];
    #pragma unroll
    for (int g=0;g<4;g++){
      #pragma unroll
      for (int st=0;st<2;st++) acc[g][st] = zero;
    }
    #pragma unroll 2
    for (int kt=0;kt<8;kt++){
      unsigned ao = (aoff0 + kt*64) ^ axor;
      bf16x8 ah = *(const bf16x8*)((const char*)hsh + ao);
      bf16x8 al = *(const bf16x8*)((const char*)hsl + ao);
      #pragma unroll
      for (int g=0;g<4;g++){
        #pragma unroll
        for (int st=0;st<2;st++){
          bf16x8 bh = *(const bf16x8*)(pbh[g][st] + (size_t)kt*512);
          bf16x8 bl = *(const bf16x8*)(pbl[g][st] + (size_t)kt*512);
          acc[g][st] = __builtin_amdgcn_mfma_f32_16x16x32_bf16(ah,bh,acc[g][st],0,0,0);
          acc[g][st] = __builtin_amdgcn_mfma_f32_16x16x32_bf16(al,bh,acc[g][st],0,0,0);
          acc[g][st] = __builtin_amdgcn_mfma_f32_16x16x32_bf16(ah,bl,acc[g][st],0,0,0);
        }
      }
    }
    __syncthreads();
    int tkr[4];
    #pragma unroll
    for (int r=0;r<4;r++) tkr[r] = toks[(e0 + kgrp*4 + r)*L_SEQ + t];
    #pragma unroll
    for (int st=0;st<2;st++){
      const int unit = w*32 + st*16 + lo16;
      #pragma unroll
      for (int r=0;r<4;r++){
        const int row = kgrp*4 + r;
        const int e = e0 + row;
        const float* ep = ectx0 + ((size_t)(dir*5 + tkr[r]))*1024 + unit;
        float zi = acc[0][st][r] + ep[0];
        float zf = acc[1][st][r] + ep[256];
        float zg = acc[2][st][r] + ep[512];
        float zo = acc[3][st][r] + ep[768];
        int ci = row*256 + unit;
        float c = sigf(zf)*cs[ci] + sigf(zi)*tanhf(zg);
        float h = sigf(zo)*tanhf(c);
        cs[ci] = c;
        unsigned short hb = f2bf(h), lb = f2bf(h - bf2f(hb));
        unsigned hoff = ((unsigned)(row*512 + unit*2)) ^ (((unsigned)(row & 7)) << 4);
        *(unsigned short*)((char*)hsh + hoff) = hb;
        *(unsigned short*)((char*)hsl + hoff) = lb;
        size_t yo = ((size_t)t*BATCH + e)*512 + dir*256 + unit;
        y0h[yo] = hb; y0l[yo] = lb;
      }
    }
    __syncthreads();
  }
}

// ---------------- context layer 1 (MFMA) ---------------- (unchanged R3)
__global__ void __launch_bounds__(512,1) ctx_l1_mfma(
    const unsigned short* __restrict__ y0h, const unsigned short* __restrict__ y0l,
    const unsigned short* __restrict__ wh, const unsigned short* __restrict__ wl,
    const float* __restrict__ bias,
    float* __restrict__ finals, int t_store)
{
  const int id  = blockIdx.x;
  const int dir = (id >> 2) & 1;
  const int bx  = ((id >> 3) << 2) | (id & 3);
  const int e0  = bx * 16;
  const int lane = threadIdx.x & 63;
  const int w    = threadIdx.x >> 6;
  const int lo16 = lane & 15, kgrp = lane >> 4;

  __shared__ unsigned short xsh[16*512];
  __shared__ unsigned short xsl[16*512];
  __shared__ unsigned short hsh[16*256];
  __shared__ unsigned short hsl[16*256];
  __shared__ float cs[16*256];
  for (int i=threadIdx.x;i<16*256;i+=512){ hsh[i]=0; hsl[i]=0; cs[i]=0.f; }

  float bb[4][2];
  #pragma unroll
  for (int g=0;g<4;g++){
    #pragma unroll
    for (int st=0;st<2;st++)
      bb[g][st] = bias[dir*1024 + g*256 + w*32 + st*16 + lo16];
  }
  const unsigned short* pbh[4][2];
  const unsigned short* pbl[4][2];
  #pragma unroll
  for (int g=0;g<4;g++){
    #pragma unroll
    for (int st=0;st<2;st++){
      int ct = g*16 + w*2 + st;
      size_t off = (size_t)dir*1024*768 + ((size_t)(ct*24)*64 + lane)*8;
      pbh[g][st] = wh + off; pbl[g][st] = wl + off;
    }
  }
  const unsigned axor = ((unsigned)(lo16 & 7)) << 4;
  __syncthreads();

  for (int s=0;s<L_SEQ;s++){
    const int t = dir ? (L_SEQ-1-s) : s;
    #pragma unroll
    for (int cc=0; cc<2; cc++){
      int ci = threadIdx.x + cc*512;
      int row = ci >> 6, cr = ci & 63;
      const unsigned short* srcbase = y0h + ((size_t)t*BATCH + e0 + row)*512 + cr*8;
      const unsigned short* srcbasel = y0l + ((size_t)t*BATCH + e0 + row)*512 + cr*8;
      uint4 vh = *(const uint4*)srcbase;
      uint4 vl = *(const uint4*)srcbasel;
      unsigned xo = ((unsigned)(row*1024 + cr*16)) ^ (((unsigned)(row & 7)) << 4);
      *(uint4*)((char*)xsh + xo) = vh;
      *(uint4*)((char*)xsl + xo) = vl;
    }
    __syncthreads();
    f32x4 zero = {0.f,0.f,0.f,0.f};
    f32x4 acc[4][2];
    #pragma unroll
    for (int g=0;g<4;g++){
      #pragma unroll
      for (int st=0;st<2;st++) acc[g][st] = zero;
    }
    #pragma unroll 2
    for (int kt=0;kt<16;kt++){
      unsigned ao = ((unsigned)(lo16*1024 + kt*64 + kgrp*16)) ^ axor;
      bf16x8 ah = *(const bf16x8*)((const char*)xsh + ao);
      bf16x8 al = *(const bf16x8*)((const char*)xsl + ao);
      #pragma unroll
      for (int g=0;g<4;g++){
        #pragma unroll
        for (int st=0;st<2;st++){
          bf16x8 bh = *(const bf16x8*)(pbh[g][st] + (size_t)kt*512);
          bf16x8 bl = *(const bf16x8*)(pbl[g][st] + (size_t)kt*512);
          acc[g][st] = __builtin_amdgcn_mfma_f32_16x16x32_bf16(ah,bh,acc[g][st],0,0,0);
          acc[g][st] = __builtin_amdgcn_mfma_f32_16x16x32_bf16(al,bh,acc[g][st],0,0,0);
          acc[g][st] = __builtin_amdgcn_mfma_f32_16x16x32_bf16(ah,bl,acc[g][st],0,0,0);
        }
      }
    }
    #pragma unroll 2
    for (int kt=16;kt<24;kt++){
      unsigned ao = ((unsigned)(lo16*512 + (kt-16)*64 + kgrp*16)) ^ axor;
      bf16x8 ah = *(const bf16x8*)((const char*)hsh + ao);
      bf16x8 al = *(const bf16x8*)((const char*)hsl + ao);
      #pragma unroll
      for (int g=0;g<4;g++){
        #pragma unroll
        for (int st=0;st<2;st++){
          bf16x8 bh = *(const bf16x8*)(pbh[g][st] + (size_t)kt*512);
          bf16x8 bl = *(const bf16x8*)(pbl[g][st] + (size_t)kt*512);
          acc[g][st] = __builtin_amdgcn_mfma_f32_16x16x32_bf16(ah,bh,acc[g][st],0,0,0);
          acc[g][st] = __builtin_amdgcn_mfma_f32_16x16x32_bf16(al,bh,acc[g][st],0,0,0);
          acc[g][st] = __builtin_amdgcn_mfma_f32_16x16x32_bf16(ah,bl,acc[g][st],0,0,0);
        }
      }
    }
    __syncthreads();
    #pragma unroll
    for (int st=0;st<2;st++){
      const int unit = w*32 + st*16 + lo16;
      #pragma unroll
      for (int r=0;r<4;r++){
        const int row = kgrp*4 + r;
        float zi = acc[0][st][r] + bb[0][st];
        float zf = acc[1][st][r] + bb[1][st];
        float zg = acc[2][st][r] + bb[2][st];
        float zo = acc[3][st][r] + bb[3][st];
        int ci = row*256 + unit;
        float c = sigf(zf)*cs[ci] + sigf(zi)*tanhf(zg);
        float h = sigf(zo)*tanhf(c);
        cs[ci] = c;
        unsigned short hb = f2bf(h), lb = f2bf(h - bf2f(hb));
        unsigned hoff = ((unsigned)(row*512 + unit*2)) ^ (((unsigned)(row & 7)) << 4);
        *(unsigned short*)((char*)hsh + hoff) = hb;
        *(unsigned short*)((char*)hsl + hoff) = lb;
        if (t == t_store)
          finals[(size_t)(e0 + row)*512 + dir*256 + unit] = h;
      }
    }
    __syncthreads();
  }
}

__global__ void combine_init2(const float* __restrict__ lf, const float* __restrict__ rf,
                              unsigned short* __restrict__ h0h, unsigned short* __restrict__ h0l,
                              unsigned short* __restrict__ h1h, unsigned short* __restrict__ h1l,
                              float* __restrict__ c0, float* __restrict__ c1){
  int i = blockIdx.x*blockDim.x + threadIdx.x;
  if (i < BATCH*HG){
    float v = 0.5f*(lf[i]+rf[i]);
    unsigned short h = f2bf(v);
    unsigned short l = f2bf(v - bf2f(h));
    h0h[i]=h; h0l[i]=l; h1h[i]=h; h1l[i]=l;
    c0[i]=0.f; c1[i]=0.f;
  }
}

// ------------- decoder layer 0 (MFMA + block-local logits/argmax) -----------
// 256 blocks x 512 thr = 1 block/CU; launch_bounds (512,1) frees VGPR budget.
__global__ void __launch_bounds__(512,1) dec_l0_mfma(
    const float* __restrict__ egen0,
    const unsigned short* __restrict__ wh, const unsigned short* __restrict__ wl,
    const unsigned short* __restrict__ hih, const unsigned short* __restrict__ hil,
    const unsigned short* __restrict__ h1ih, const unsigned short* __restrict__ h1il,
    unsigned short* __restrict__ hoh, unsigned short* __restrict__ hol,
    float* __restrict__ cst,
    const float* __restrict__ outW, const float* __restrict__ outb,
    float* __restrict__ out, int t)
{
  const int bid = blockIdx.x;
  const int by = bid & 15;
  const int bx = bid >> 4;
  const int e0 = bx * 64;
  const int lane = threadIdx.x & 63;
  const int w = threadIdx.x >> 6;
  const int wm = w & 3, wu = w >> 2;
  const int ut = by*2 + wu;
  const int lo16 = lane & 15, kgrp = lane >> 4;
  const int arow = e0 + wm*16 + lo16;
  const int u = ut*16 + lo16;
  const int r0 = e0 + wm*16 + kgrp*4;

  const unsigned short* pah = hih + (size_t)arow*512 + kgrp*8;
  const unsigned short* pal = hil + (size_t)arow*512 + kgrp*8;
  const unsigned short* pb[8];
  #pragma unroll
  for (int q=0;q<4;q++){
    size_t off = ((size_t)(q*32+ut)*16*64 + lane)*8;   // KT=16
    pb[q]   = wh + off;
    pb[q+4] = wl + off;
  }
  const f32x4 z4 = {0.f,0.f,0.f,0.f};
  f32x4 aHH[4]={z4,z4,z4,z4}, aLH[4]={z4,z4,z4,z4}, aHL[4]={z4,z4,z4,z4};

  #pragma unroll 2
  for (int ks=0; ks<16; ks++){
    bf16x8 ah = *(const bf16x8*)(pah + (size_t)ks*32);
    bf16x8 al = *(const bf16x8*)(pal + (size_t)ks*32);
    #pragma unroll
    for (int q=0;q<4;q++){
      bf16x8 bh = *(const bf16x8*)(pb[q]   + (size_t)ks*512);
      bf16x8 bl = *(const bf16x8*)(pb[q+4] + (size_t)ks*512);
      aHH[q] = __builtin_amdgcn_mfma_f32_16x16x32_bf16(ah, bh, aHH[q], 0,0,0);
      aLH[q] = __builtin_amdgcn_mfma_f32_16x16x32_bf16(al, bh, aLH[q], 0,0,0);
      aHL[q] = __builtin_amdgcn_mfma_f32_16x16x32_bf16(ah, bl, aHL[q], 0,0,0);
    }
  }

  // ---- logits of step t-1 for rows r0..r0+3, per 16-lane group ----
  int tkr[4] = {0,0,0,0};
  if (t > 0){
    float acc5[4][5];
    #pragma unroll
    for (int r=0;r<4;r++){
      #pragma unroll
      for (int v=0;v<5;v++) acc5[r][v]=0.f;
    }
    #pragma unroll
    for (int j=0;j<4;j++){
      const int ub = lo16*32 + j*8;          // 8 consecutive units per chunk
      f32x4 w0[5], w1[5];
      #pragma unroll
      for (int v=0;v<5;v++){
        const float* wp = outW + v*512 + ub;
        w0[v] = *(const f32x4*)(wp);
        w1[v] = *(const f32x4*)(wp+4);
      }
      #pragma unroll
      for (int r=0;r<4;r++){
        const unsigned short* hh = h1ih + (size_t)(r0+r)*512 + ub;
        const unsigned short* hl = h1il + (size_t)(r0+r)*512 + ub;
        bf16x8 vh = *(const bf16x8*)hh;
        bf16x8 vl = *(const bf16x8*)hl;
        #pragma unroll
        for (int m=0;m<4;m++){
          float hv = bf2f((unsigned short)vh[m]) + bf2f((unsigned short)vl[m]);
          #pragma unroll
          for (int v=0;v<5;v++) acc5[r][v] += hv * w0[v][m];
        }
        #pragma unroll
        for (int m=0;m<4;m++){
          float hv = bf2f((unsigned short)vh[m+4]) + bf2f((unsigned short)vl[m+4]);
          #pragma unroll
          for (int v=0;v<5;v++) acc5[r][v] += hv * w1[v][m];
        }
      }
    }
    #pragma unroll
    for (int r=0;r<4;r++){
      #pragma unroll
      for (int v=0;v<5;v++){
        float s = acc5[r][v];
        s += __shfl_xor(s, 1);
        s += __shfl_xor(s, 2);
        s += __shfl_xor(s, 4);
        s += __shfl_xor(s, 8);
        acc5[r][v] = s + outb[v];
      }
      float best = acc5[r][0]; int tk = 0;
      if (acc5[r][1] > best){ best = acc5[r][1]; tk = 1; }
      if (acc5[r][2] > best){ best = acc5[r][2]; tk = 2; }
      if (acc5[r][3] > best){ best = acc5[r][3]; tk = 3; }
      if (acc5[r][4] > best){ best = acc5[r][4]; tk = 4; }
      tkr[r] = tk;
    }
    if (by == 0 && wu == 0 && lo16 == 0){
      #pragma unroll
      for (int r=0;r<4;r++){
        float* op = out + ((size_t)(r0+r)*TDEC + (t-1))*5;
        #pragma unroll
        for (int v=0;v<5;v++) op[v] = acc5[r][v];
      }
    }
  }

  #pragma unroll
  for (int r=0;r<4;r++){
    const int e = r0 + r;
    const float* ep = egen0 + (size_t)tkr[r]*2048 + u;
    float zi = aHH[0][r]+aLH[0][r]+aHL[0][r] + ep[0];
    float zf = aHH[1][r]+aLH[1][r]+aHL[1][r] + ep[512];
    float zg = aHH[2][r]+aLH[2][r]+aHL[2][r] + ep[1024];
    float zo = aHH[3][r]+aLH[3][r]+aHL[3][r] + ep[1536];
    const size_t idx = (size_t)e*512 + u;
    float c = sigf(zf)*cst[idx] + sigf(zi)*tanhf(zg);
    float h = sigf(zo)*tanhf(c);
    cst[idx] = c;
    unsigned short hb = f2bf(h);
    hoh[idx] = hb;
    hol[idx] = f2bf(h - bf2f(hb));
  }
}

// ------------- decoder layer 1 (pure LSTM, sequential K-loops) --------------
// K=1024 = [x(=h0out); h1prev]. R4-proven form: x loop then h loop, 12 chains.
__global__ void __launch_bounds__(512,1) dec_l1_mfma(
    const unsigned short* __restrict__ xh, const unsigned short* __restrict__ xl,
    const unsigned short* __restrict__ wh, const unsigned short* __restrict__ wl,
    const float* __restrict__ bias,
    const unsigned short* __restrict__ hih, const unsigned short* __restrict__ hil,
    unsigned short* __restrict__ hoh, unsigned short* __restrict__ hol,
    float* __restrict__ cst)
{
  const int bid = blockIdx.x;
  const int by = bid & 15;
  const int bx = bid >> 4;
  const int e0 = bx * 64;
  const int lane = threadIdx.x & 63;
  const int w = threadIdx.x >> 6;
  const int wm = w & 3, wu = w >> 2;
  const int ut = by*2 + wu;
  const int lo16 = lane & 15, kgrp = lane >> 4;
  const int arow = e0 + wm*16 + lo16;
  const int u = ut*16 + lo16;
  const int r0 = e0 + wm*16 + kgrp*4;

  const unsigned short* pxh = xh  + (size_t)arow*512 + kgrp*8;
  const unsigned short* pxl = xl  + (size_t)arow*512 + kgrp*8;
  const unsigned short* pah = hih + (size_t)arow*512 + kgrp*8;
  const unsigned short* pal = hil + (size_t)arow*512 + kgrp*8;
  const unsigned short* pb[8];
  #pragma unroll
  for (int q=0;q<4;q++){
    size_t off = ((size_t)(q*32+ut)*32*64 + lane)*8;   // KT=32
    pb[q]   = wh + off;
    pb[q+4] = wl + off;
  }
  const f32x4 z4 = {0.f,0.f,0.f,0.f};
  f32x4 aHH[4]={z4,z4,z4,z4}, aLH[4]={z4,z4,z4,z4}, aHL[4]={z4,z4,z4,z4};

  #pragma unroll 2
  for (int ks=0; ks<16; ks++){          // k 0..511 : x = h0out
    bf16x8 ah = *(const bf16x8*)(pxh + (size_t)ks*32);
    bf16x8 al = *(const bf16x8*)(pxl + (size_t)ks*32);
    #pragma unroll
    for (int q=0;q<4;q++){
      bf16x8 bh = *(const bf16x8*)(pb[q]   + (size_t)ks*512);
      bf16x8 bl = *(const bf16x8*)(pb[q+4] + (size_t)ks*512);
      aHH[q] = __builtin_amdgcn_mfma_f32_16x16x32_bf16(ah, bh, aHH[q], 0,0,0);
      aLH[q] = __builtin_amdgcn_mfma_f32_16x16x32_bf16(al, bh, aLH[q], 0,0,0);
      aHL[q] = __builtin_amdgcn_mfma_f32_16x16x32_bf16(ah, bl, aHL[q], 0,0,0);
    }
  }
  #pragma unroll 2
  for (int ks=16; ks<32; ks++){         // k 512..1023 : h1 prev
    bf16x8 ah = *(const bf16x8*)(pah + (size_t)(ks-16)*32);
    bf16x8 al = *(const bf16x8*)(pal + (size_t)(ks-16)*32);
    #pragma unroll
    for (int q=0;q<4;q++){
      bf16x8 bh = *(const bf16x8*)(pb[q]   + (size_t)ks*512);
      bf16x8 bl = *(const bf16x8*)(pb[q+4] + (size_t)ks*512);
      aHH[q] = __builtin_amdgcn_mfma_f32_16x16x32_bf16(ah, bh, aHH[q], 0,0,0);
      aLH[q] = __builtin_amdgcn_mfma_f32_16x16x32_bf16(al, bh, aLH[q], 0,0,0);
      aHL[q] = __builtin_amdgcn_mfma_f32_16x16x32_bf16(ah, bl, aHL[q], 0,0,0);
    }
  }

  const float b0 = bias[u], b1 = bias[512+u], b2 = bias[1024+u], b3 = bias[1536+u];
  #pragma unroll
  for (int r=0;r<4;r++){
    const int e = r0 + r;
    float zi = aHH[0][r]+aLH[0][r]+aHL[0][r] + b0;
    float zf = aHH[1][r]+aLH[1][r]+aHL[1][r] + b1;
    float zg = aHH[2][r]+aLH[2][r]+aHL[2][r] + b2;
    float zo = aHH[3][r]+aLH[3][r]+aHL[3][r] + b3;
    const size_t idx = (size_t)e*512 + u;
    float c = sigf(zf)*cst[idx] + sigf(zi)*tanhf(zg);
    float h = sigf(zo)*tanhf(c);
    cst[idx] = c;
    unsigned short hb = f2bf(h);
    hoh[idx] = hb;
    hol[idx] = f2bf(h - bf2f(hb));
  }
}

// final-step logits (t = TDEC-1): one wave per batch elem
__global__ void dec_outF(const unsigned short* __restrict__ h1h,
                         const unsigned short* __restrict__ h1l,
                         const float* __restrict__ outW,
                         const float* __restrict__ outb,
                         float* __restrict__ out){
  const int lane = threadIdx.x & 63;
  const int e = blockIdx.x*4 + (threadIdx.x >> 6);
  const unsigned short* hh = h1h + (size_t)e*512;
  const unsigned short* hl = h1l + (size_t)e*512;
  float s0=0,s1=0,s2=0,s3=0,s4=0;
  for (int k=lane;k<512;k+=64){
    float hv = bf2f(hh[k]) + bf2f(hl[k]);
    s0 += hv*outW[k];
    s1 += hv*outW[512+k];
    s2 += hv*outW[1024+k];
    s3 += hv*outW[1536+k];
    s4 += hv*outW[2048+k];
  }
  #pragma unroll
  for (int off=32; off>0; off>>=1){
    s0 += __shfl_down(s0, off);
    s1 += __shfl_down(s1, off);
    s2 += __shfl_down(s2, off);
    s3 += __shfl_down(s3, off);
    s4 += __shfl_down(s4, off);
  }
  if (lane==0){
    float* op = out + ((size_t)e*TDEC + (TDEC-1))*5;
    op[0]=s0+outb[0]; op[1]=s1+outb[1]; op[2]=s2+outb[2];
    op[3]=s3+outb[3]; op[4]=s4+outb[4];
  }
}

extern "C" void kernel_launch(void* const* d_in, const int* in_sizes, int n_in,
                              void* d_out, int out_size, void* d_ws, size_t ws_size,
                              hipStream_t stream){
  (void)in_sizes; (void)n_in; (void)out_size;
  const int*   leftc    = (const int*)d_in[0];
  const int*   rightc   = (const int*)d_in[1];
  const float* emb      = (const float*)d_in[3];
  const float* ctx0_Wih = (const float*)d_in[4];
  const float* ctx0_Whh = (const float*)d_in[5];
  const float* ctx0_b   = (const float*)d_in[6];
  const float* ctx1_Wih = (const float*)d_in[7];
  const float* ctx1_Whh = (const float*)d_in[8];
  const float* ctx1_b   = (const float*)d_in[9];
  const float* gen0_Wih = (const float*)d_in[10];
  const float* gen0_Whh = (const float*)d_in[11];
  const float* gen0_b   = (const float*)d_in[12];
  const float* gen1_Wih = (const float*)d_in[13];
  const float* gen1_Whh = (const float*)d_in[14];
  const float* gen1_b   = (const float*)d_in[15];
  const float* out_W    = (const float*)d_in[16];
  const float* out_b    = (const float*)d_in[17];
  float* out = (float*)d_out;

  char* p = (char*)d_ws;
  auto carve = [&](size_t nfloats)->float*{
    float* r = (float*)p;
    p += ((nfloats*sizeof(float) + 255) & ~(size_t)255);
    return r;
  };
  auto carveu = [&](size_t nush)->unsigned short*{
    return (unsigned short*)carve((nush + 1)/2);
  };
  float* ectx0  = carve(2*5*1024);
  float* egen0  = carve(5*2048);
  float* leftF  = carve((size_t)BATCH*HG);
  float* rightF = carve((size_t)BATCH*HG);
  float* c0s    = carve((size_t)BATCH*HG);
  float* c1s    = carve((size_t)BATCH*HG);
  unsigned short* c0pkh = carveu((size_t)2*1024*256);
  unsigned short* c0pkl = carveu((size_t)2*1024*256);
  unsigned short* c1pkh = carveu((size_t)2*1024*768);
  unsigned short* c1pkl = carveu((size_t)2*1024*768);
  unsigned short* pk0h = carveu((size_t)2048*512);
  unsigned short* pk0l = carveu((size_t)2048*512);
  unsigned short* pk1h = carveu((size_t)2048*1024);
  unsigned short* pk1l = carveu((size_t)2048*1024);
  unsigned short* h0ha = carveu((size_t)BATCH*HG);
  unsigned short* h0la = carveu((size_t)BATCH*HG);
  unsigned short* h0hb = carveu((size_t)BATCH*HG);
  unsigned short* h0lb = carveu((size_t)BATCH*HG);
  unsigned short* h1ha = carveu((size_t)BATCH*HG);
  unsigned short* h1la = carveu((size_t)BATCH*HG);
  unsigned short* h1hb = carveu((size_t)BATCH*HG);
  unsigned short* h1lb = carveu((size_t)BATCH*HG);
  unsigned short* y0h = carveu((size_t)L_SEQ*BATCH*512);   // 105 MB
  unsigned short* y0l = carveu((size_t)L_SEQ*BATCH*512);   // 105 MB
  if ((size_t)(p - (char*)d_ws) > ws_size) return;  // insufficient workspace -> loud fail

  // weight packs (fragment-linear bf16 hi/lo)
  for (int d=0; d<2; d++){
    pack_w<<<128, 256, 0, stream>>>(ctx0_Whh + (size_t)d*1024*256, 1024, 256, 8, 0,
                                    c0pkh + (size_t)d*262144, c0pkl + (size_t)d*262144);
    pack_w<<<256, 256, 0, stream>>>(ctx1_Wih + (size_t)d*1024*512, 1024, 512, 24, 0,
                                    c1pkh + (size_t)d*786432, c1pkl + (size_t)d*786432);
    pack_w<<<128, 256, 0, stream>>>(ctx1_Whh + (size_t)d*1024*256, 1024, 256, 24, 16,
                                    c1pkh + (size_t)d*786432, c1pkl + (size_t)d*786432);
  }
  pack_w<<<512, 256, 0, stream>>>(gen0_Whh, 2048, 512, 16,  0, pk0h, pk0l);
  pack_w<<<512, 256, 0, stream>>>(gen1_Wih, 2048, 512, 32,  0, pk1h, pk1l);
  pack_w<<<512, 256, 0, stream>>>(gen1_Whh, 2048, 512, 32, 16, pk1h, pk1l);

  embprep<<<(20480+255)/256, 256, 0, stream>>>(emb, ctx0_Wih, ctx0_b,
                                               gen0_Wih, gen0_b, ectx0, egen0);

  // left encode (finals at t=99), then right (finals at t=0); y0 reused
  ctx_l0_mfma<<<128, 512, 0, stream>>>(leftc, ectx0, c0pkh, c0pkl, y0h, y0l);
  ctx_l1_mfma<<<128, 512, 0, stream>>>(y0h, y0l, c1pkh, c1pkl, ctx1_b, leftF, L_SEQ-1);
  ctx_l0_mfma<<<128, 512, 0, stream>>>(rightc, ectx0, c0pkh, c0pkl, y0h, y0l);
  ctx_l1_mfma<<<128, 512, 0, stream>>>(y0h, y0l, c1pkh, c1pkl, ctx1_b, rightF, 0);

  combine_init2<<<(BATCH*HG+255)/256, 256, 0, stream>>>(leftF, rightF,
                                                        h0ha, h0la, h1ha, h1la,
                                                        c0s, c1s);

  for (int t=0;t<TDEC;t++){
    unsigned short* h0ih = (t&1)? h0hb : h0ha;
    unsigned short* h0il = (t&1)? h0lb : h0la;
    unsigned short* h0oh = (t&1)? h0ha : h0hb;
    unsigned short* h0ol = (t&1)? h0la : h0lb;
    unsigned short* h1ih = (t&1)? h1hb : h1ha;
    unsigned short* h1il = (t&1)? h1lb : h1la;
    unsigned short* h1oh = (t&1)? h1ha : h1hb;
    unsigned short* h1ol = (t&1)? h1la : h1lb;
    dec_l0_mfma<<<256, 512, 0, stream>>>(egen0, pk0h, pk0l,
                                         h0ih, h0il, h1ih, h1il,
                                         h0oh, h0ol, c0s,
                                         out_W, out_b, out, t);
    dec_l1_mfma<<<256, 512, 0, stream>>>(h0oh, h0ol, pk1h, pk1l, gen1_b,
                                         h1ih, h1il, h1oh, h1ol, c1s);
  }
  // t = TDEC-1 logits (h1 final lives in the 'a' buffers after odd t=255)
  dec_outF<<<256, 256, 0, stream>>>(h1ha, h1la, out_W, out_b, out);
}

// Round 8
// 22964.290 us; speedup vs baseline: 1.9885x; 1.2218x over previous
//
#include <hip/hip_runtime.h>

// LSTMGapFiller R9: async weight staging. Decoder kernels stage their packed
// B-slices into LDS via __builtin_amdgcn_global_load_lds (fire-and-forget
// queue -> weight refetch after the per-launch L2 invalidation streams at BW
// instead of ~250 GB/s latency-bound; guide Common-mistake #1 / m97 lever).
// Packed layout is fragment-linear so each 1KB line = one wave-instr. 4-ks
// chunks, double-buffered (128 KB LDS). Also kills the 4x redundant B-loads
// across row-tile waves and frees ~64 VGPRs of B-fragments. Everything else
// identical to R8 (fused logits/argmax, no atomics, R3 context stack).

#define L_SEQ 100
#define BATCH 1024
#define HCTX 256
#define HG 512
#define TDEC 256

typedef __attribute__((ext_vector_type(8))) short bf16x8;
typedef __attribute__((ext_vector_type(4))) float f32x4;

__device__ __forceinline__ float sigf(float x){ return 1.0f/(1.0f+expf(-x)); }
__device__ __forceinline__ unsigned short f2bf(float x){
  unsigned int u = __float_as_uint(x);
  return (unsigned short)((u + 0x7fffu + ((u>>16)&1u)) >> 16);   // RNE
}
__device__ __forceinline__ float bf2f(unsigned short h){
  return __uint_as_float(((unsigned int)h)<<16);
}

// Pack W[G][K] (fp32, row-major) into MFMA-fragment-linear bf16 hi/lo.
__global__ void pack_w(const float* __restrict__ W, int G, int K, int KTtot, int kt0,
                       unsigned short* __restrict__ hi, unsigned short* __restrict__ lo){
  int idx = blockIdx.x*blockDim.x + threadIdx.x;
  int kt_n = K/32;
  int total = (G/16)*kt_n*64;
  if (idx >= total) return;
  int lane = idx & 63;
  int ktl = (idx>>6) % kt_n;
  int gt  = (idx>>6) / kt_n;
  int g = gt*16 + (lane & 15);
  int k = ktl*32 + (lane>>4)*8;
  const float* src = W + (size_t)g*K + k;
  size_t dst = (((size_t)gt*KTtot + (kt0 + ktl))*64 + lane)*8;
  #pragma unroll
  for (int j=0;j<8;j++){
    float x = src[j];
    unsigned short h = f2bf(x);
    hi[dst+j] = h;
    lo[dst+j] = f2bf(x - bf2f(h));
  }
}

// embedding projections (vocab=5)
__global__ void embprep(const float* __restrict__ emb,
                        const float* __restrict__ c0Wih, const float* __restrict__ c0b,
                        const float* __restrict__ g0Wih, const float* __restrict__ g0b,
                        float* __restrict__ ectx0, float* __restrict__ egen0){
  int idx = blockIdx.x*blockDim.x + threadIdx.x;
  if (idx < 2*5*1024){
    int d = idx / 5120;
    int v = (idx / 1024) % 5;
    int j = idx % 1024;
    const float* w = c0Wih + ((size_t)d*1024 + j)*64;
    const float* e = emb + v*64;
    float s = c0b[d*1024 + j];
    #pragma unroll
    for (int k=0;k<64;k++) s += e[k]*w[k];
    ectx0[idx] = s;
  } else if (idx < 2*5*1024 + 5*2048){
    int i2 = idx - 10240;
    int v = i2 / 2048;
    int j = i2 % 2048;
    const float* w = g0Wih + (size_t)j*64;
    const float* e = emb + v*64;
    float s = g0b[j];
    #pragma unroll
    for (int k=0;k<64;k++) s += e[k]*w[k];
    egen0[i2] = s;
  }
}

// ---------------- context layer 0 (MFMA) ---------------- (unchanged R3)
__global__ void __launch_bounds__(512,1) ctx_l0_mfma(
    const int* __restrict__ toks,
    const float* __restrict__ ectx0,
    const unsigned short* __restrict__ wh, const unsigned short* __restrict__ wl,
    unsigned short* __restrict__ y0h, unsigned short* __restrict__ y0l)
{
  const int id  = blockIdx.x;
  const int dir = (id >> 2) & 1;
  const int bx  = ((id >> 3) << 2) | (id & 3);
  const int e0  = bx * 16;
  const int lane = threadIdx.x & 63;
  const int w    = threadIdx.x >> 6;
  const int lo16 = lane & 15, kgrp = lane >> 4;

  __shared__ unsigned short hsh[16*256];
  __shared__ unsigned short hsl[16*256];
  __shared__ float cs[16*256];
  for (int i=threadIdx.x;i<16*256;i+=512){ hsh[i]=0; hsl[i]=0; cs[i]=0.f; }
  __syncthreads();

  const unsigned short* pbh[4][2];
  const unsigned short* pbl[4][2];
  #pragma unroll
  for (int g=0;g<4;g++){
    #pragma unroll
    for (int st=0;st<2;st++){
      int ct = g*16 + w*2 + st;
      size_t off = (size_t)dir*1024*256 + ((size_t)(ct*8)*64 + lane)*8;
      pbh[g][st] = wh + off; pbl[g][st] = wl + off;
    }
  }
  const unsigned aoff0 = (unsigned)(lo16*512 + kgrp*16);
  const unsigned axor  = ((unsigned)(lo16 & 7)) << 4;

  for (int s=0;s<L_SEQ;s++){
    const int t = dir ? (L_SEQ-1-s) : s;
    f32x4 zero = {0.f,0.f,0.f,0.f};
    f32x4 acc[4][2];
    #pragma unroll
    for (int g=0;g<4;g++){
      #pragma unroll
      for (int st=0;st<2;st++) acc[g][st] = zero;
    }
    #pragma unroll 2
    for (int kt=0;kt<8;kt++){
      unsigned ao = (aoff0 + kt*64) ^ axor;
      bf16x8 ah = *(const bf16x8*)((const char*)hsh + ao);
      bf16x8 al = *(const bf16x8*)((const char*)hsl + ao);
      #pragma unroll
      for (int g=0;g<4;g++){
        #pragma unroll
        for (int st=0;st<2;st++){
          bf16x8 bh = *(const bf16x8*)(pbh[g][st] + (size_t)kt*512);
          bf16x8 bl = *(const bf16x8*)(pbl[g][st] + (size_t)kt*512);
          acc[g][st] = __builtin_amdgcn_mfma_f32_16x16x32_bf16(ah,bh,acc[g][st],0,0,0);
          acc[g][st] = __builtin_amdgcn_mfma_f32_16x16x32_bf16(al,bh,acc[g][st],0,0,0);
          acc[g][st] = __builtin_amdgcn_mfma_f32_16x16x32_bf16(ah,bl,acc[g][st],0,0,0);
        }
      }
    }
    __syncthreads();
    int tkr[4];
    #pragma unroll
    for (int r=0;r<4;r++) tkr[r] = toks[(e0 + kgrp*4 + r)*L_SEQ + t];
    #pragma unroll
    for (int st=0;st<2;st++){
      const int unit = w*32 + st*16 + lo16;
      #pragma unroll
      for (int r=0;r<4;r++){
        const int row = kgrp*4 + r;
        const int e = e0 + row;
        const float* ep = ectx0 + ((size_t)(dir*5 + tkr[r]))*1024 + unit;
        float zi = acc[0][st][r] + ep[0];
        float zf = acc[1][st][r] + ep[256];
        float zg = acc[2][st][r] + ep[512];
        float zo = acc[3][st][r] + ep[768];
        int ci = row*256 + unit;
        float c = sigf(zf)*cs[ci] + sigf(zi)*tanhf(zg);
        float h = sigf(zo)*tanhf(c);
        cs[ci] = c;
        unsigned short hb = f2bf(h), lb = f2bf(h - bf2f(hb));
        unsigned hoff = ((unsigned)(row*512 + unit*2)) ^ (((unsigned)(row & 7)) << 4);
        *(unsigned short*)((char*)hsh + hoff) = hb;
        *(unsigned short*)((char*)hsl + hoff) = lb;
        size_t yo = ((size_t)t*BATCH + e)*512 + dir*256 + unit;
        y0h[yo] = hb; y0l[yo] = lb;
      }
    }
    __syncthreads();
  }
}

// ---------------- context layer 1 (MFMA) ---------------- (unchanged R3)
__global__ void __launch_bounds__(512,1) ctx_l1_mfma(
    const unsigned short* __restrict__ y0h, const unsigned short* __restrict__ y0l,
    const unsigned short* __restrict__ wh, const unsigned short* __restrict__ wl,
    const float* __restrict__ bias,
    float* __restrict__ finals, int t_store)
{
  const int id  = blockIdx.x;
  const int dir = (id >> 2) & 1;
  const int bx  = ((id >> 3) << 2) | (id & 3);
  const int e0  = bx * 16;
  const int lane = threadIdx.x & 63;
  const int w    = threadIdx.x >> 6;
  const int lo16 = lane & 15, kgrp = lane >> 4;

  __shared__ unsigned short xsh[16*512];
  __shared__ unsigned short xsl[16*512];
  __shared__ unsigned short hsh[16*256];
  __shared__ unsigned short hsl[16*256];
  __shared__ float cs[16*256];
  for (int i=threadIdx.x;i<16*256;i+=512){ hsh[i]=0; hsl[i]=0; cs[i]=0.f; }

  float bb[4][2];
  #pragma unroll
  for (int g=0;g<4;g++){
    #pragma unroll
    for (int st=0;st<2;st++)
      bb[g][st] = bias[dir*1024 + g*256 + w*32 + st*16 + lo16];
  }
  const unsigned short* pbh[4][2];
  const unsigned short* pbl[4][2];
  #pragma unroll
  for (int g=0;g<4;g++){
    #pragma unroll
    for (int st=0;st<2;st++){
      int ct = g*16 + w*2 + st;
      size_t off = (size_t)dir*1024*768 + ((size_t)(ct*24)*64 + lane)*8;
      pbh[g][st] = wh + off; pbl[g][st] = wl + off;
    }
  }
  const unsigned axor = ((unsigned)(lo16 & 7)) << 4;
  __syncthreads();

  for (int s=0;s<L_SEQ;s++){
    const int t = dir ? (L_SEQ-1-s) : s;
    #pragma unroll
    for (int cc=0; cc<2; cc++){
      int ci = threadIdx.x + cc*512;
      int row = ci >> 6, cr = ci & 63;
      const unsigned short* srcbase = y0h + ((size_t)t*BATCH + e0 + row)*512 + cr*8;
      const unsigned short* srcbasel = y0l + ((size_t)t*BATCH + e0 + row)*512 + cr*8;
      uint4 vh = *(const uint4*)srcbase;
      uint4 vl = *(const uint4*)srcbasel;
      unsigned xo = ((unsigned)(row*1024 + cr*16)) ^ (((unsigned)(row & 7)) << 4);
      *(uint4*)((char*)xsh + xo) = vh;
      *(uint4*)((char*)xsl + xo) = vl;
    }
    __syncthreads();
    f32x4 zero = {0.f,0.f,0.f,0.f};
    f32x4 acc[4][2];
    #pragma unroll
    for (int g=0;g<4;g++){
      #pragma unroll
      for (int st=0;st<2;st++) acc[g][st] = zero;
    }
    #pragma unroll 2
    for (int kt=0;kt<16;kt++){
      unsigned ao = ((unsigned)(lo16*1024 + kt*64 + kgrp*16)) ^ axor;
      bf16x8 ah = *(const bf16x8*)((const char*)xsh + ao);
      bf16x8 al = *(const bf16x8*)((const char*)xsl + ao);
      #pragma unroll
      for (int g=0;g<4;g++){
        #pragma unroll
        for (int st=0;st<2;st++){
          bf16x8 bh = *(const bf16x8*)(pbh[g][st] + (size_t)kt*512);
          bf16x8 bl = *(const bf16x8*)(pbl[g][st] + (size_t)kt*512);
          acc[g][st] = __builtin_amdgcn_mfma_f32_16x16x32_bf16(ah,bh,acc[g][st],0,0,0);
          acc[g][st] = __builtin_amdgcn_mfma_f32_16x16x32_bf16(al,bh,acc[g][st],0,0,0);
          acc[g][st] = __builtin_amdgcn_mfma_f32_16x16x32_bf16(ah,bl,acc[g][st],0,0,0);
        }
      }
    }
    #pragma unroll 2
    for (int kt=16;kt<24;kt++){
      unsigned ao = ((unsigned)(lo16*512 + (kt-16)*64 + kgrp*16)) ^ axor;
      bf16x8 ah = *(const bf16x8*)((const char*)hsh + ao);
      bf16x8 al = *(const bf16x8*)((const char*)hsl + ao);
      #pragma unroll
      for (int g=0;g<4;g++){
        #pragma unroll
        for (int st=0;st<2;st++){
          bf16x8 bh = *(const bf16x8*)(pbh[g][st] + (size_t)kt*512);
          bf16x8 bl = *(const bf16x8*)(pbl[g][st] + (size_t)kt*512);
          acc[g][st] = __builtin_amdgcn_mfma_f32_16x16x32_bf16(ah,bh,acc[g][st],0,0,0);
          acc[g][st] = __builtin_amdgcn_mfma_f32_16x16x32_bf16(al,bh,acc[g][st],0,0,0);
          acc[g][st] = __builtin_amdgcn_mfma_f32_16x16x32_bf16(ah,bl,acc[g][st],0,0,0);
        }
      }
    }
    __syncthreads();
    #pragma unroll
    for (int st=0;st<2;st++){
      const int unit = w*32 + st*16 + lo16;
      #pragma unroll
      for (int r=0;r<4;r++){
        const int row = kgrp*4 + r;
        float zi = acc[0][st][r] + bb[0][st];
        float zf = acc[1][st][r] + bb[1][st];
        float zg = acc[2][st][r] + bb[2][st];
        float zo = acc[3][st][r] + bb[3][st];
        int ci = row*256 + unit;
        float c = sigf(zf)*cs[ci] + sigf(zi)*tanhf(zg);
        float h = sigf(zo)*tanhf(c);
        cs[ci] = c;
        unsigned short hb = f2bf(h), lb = f2bf(h - bf2f(hb));
        unsigned hoff = ((unsigned)(row*512 + unit*2)) ^ (((unsigned)(row & 7)) << 4);
        *(unsigned short*)((char*)hsh + hoff) = hb;
        *(unsigned short*)((char*)hsl + hoff) = lb;
        if (t == t_store)
          finals[(size_t)(e0 + row)*512 + dir*256 + unit] = h;
      }
    }
    __syncthreads();
  }
}

__global__ void combine_init2(const float* __restrict__ lf, const float* __restrict__ rf,
                              unsigned short* __restrict__ h0h, unsigned short* __restrict__ h0l,
                              unsigned short* __restrict__ h1h, unsigned short* __restrict__ h1l,
                              float* __restrict__ c0, float* __restrict__ c1){
  int i = blockIdx.x*blockDim.x + threadIdx.x;
  if (i < BATCH*HG){
    float v = 0.5f*(lf[i]+rf[i]);
    unsigned short h = f2bf(v);
    unsigned short l = f2bf(v - bf2f(h));
    h0h[i]=h; h0l[i]=l; h1h[i]=h; h1l[i]=l;
    c0[i]=0.f; c1[i]=0.f;
  }
}

// ------------- decoder layer 0 (staged MFMA + block-local logits/argmax) ----
// 256 blocks x 512 thr = 1 block/CU. B-slices staged to LDS async (4-ks
// chunks, double-buffered). Each 1KB line = one global_load_lds wave-instr.
__global__ void __launch_bounds__(512,1) dec_l0_mfma(
    const float* __restrict__ egen0,
    const unsigned short* __restrict__ wh, const unsigned short* __restrict__ wl,
    const unsigned short* __restrict__ hih, const unsigned short* __restrict__ hil,
    const unsigned short* __restrict__ h1ih, const unsigned short* __restrict__ h1il,
    unsigned short* __restrict__ hoh, unsigned short* __restrict__ hol,
    float* __restrict__ cst,
    const float* __restrict__ outW, const float* __restrict__ outb,
    float* __restrict__ out, int t)
{
  __shared__ unsigned short bsm[2][32768];    // 2 x 64 KB chunks
  const int bid = blockIdx.x;
  const int by = bid & 15;
  const int bx = bid >> 4;
  const int e0 = bx * 64;
  const int lane = threadIdx.x & 63;
  const int w = threadIdx.x >> 6;
  const int wm = w & 3, wu = w >> 2;
  const int ut = by*2 + wu;
  const int lo16 = lane & 15, kgrp = lane >> 4;
  const int arow = e0 + wm*16 + lo16;
  const int u = ut*16 + lo16;
  const int r0 = e0 + wm*16 + kgrp*4;

  const unsigned short* pah = hih + (size_t)arow*512 + kgrp*8;
  const unsigned short* pal = hil + (size_t)arow*512 + kgrp*8;

  // stage chunk c: 4 ks x 2 wu x 4 q x 2 hl = 64 lines x 1KB (KT=16)
  auto STAGE = [&](int c){
    #pragma unroll
    for (int i=0;i<8;i++){
      int id = w*8 + i;
      int hl  = id & 1;
      int q   = (id >> 1) & 3;
      int wu2 = (id >> 3) & 1;
      int ksl = id >> 4;
      int ks  = c*4 + ksl;
      const unsigned short* src = (hl ? wl : wh)
          + (((size_t)(q*32 + by*2 + wu2)*16 + ks)*64 + lane)*8;
      __builtin_amdgcn_global_load_lds((const void*)src,
          (void*)(&bsm[c & 1][id*512]), 16, 0, 0);
    }
  };

  const f32x4 z4 = {0.f,0.f,0.f,0.f};
  f32x4 aHH[4]={z4,z4,z4,z4}, aLH[4]={z4,z4,z4,z4}, aHL[4]={z4,z4,z4,z4};

  STAGE(0);
  __syncthreads();
  for (int c=0; c<4; c++){
    if (c+1 < 4) STAGE(c+1);
    const unsigned short* bb = &bsm[c&1][0];
    #pragma unroll
    for (int ksl=0; ksl<4; ksl++){
      int ks = c*4 + ksl;
      bf16x8 ah = *(const bf16x8*)(pah + (size_t)ks*32);
      bf16x8 al = *(const bf16x8*)(pal + (size_t)ks*32);
      #pragma unroll
      for (int q=0;q<4;q++){
        int fid = ((ksl*2 + wu)*4 + q)*2;
        bf16x8 bh = *(const bf16x8*)(bb + fid*512     + lane*8);
        bf16x8 bl = *(const bf16x8*)(bb + fid*512+512 + lane*8);
        aHH[q] = __builtin_amdgcn_mfma_f32_16x16x32_bf16(ah, bh, aHH[q], 0,0,0);
        aLH[q] = __builtin_amdgcn_mfma_f32_16x16x32_bf16(al, bh, aLH[q], 0,0,0);
        aHL[q] = __builtin_amdgcn_mfma_f32_16x16x32_bf16(ah, bl, aHL[q], 0,0,0);
      }
    }
    __syncthreads();
  }

  // ---- logits of step t-1 for rows r0..r0+3, per 16-lane group ----
  int tkr[4] = {0,0,0,0};
  if (t > 0){
    float acc5[4][5];
    #pragma unroll
    for (int r=0;r<4;r++){
      #pragma unroll
      for (int v=0;v<5;v++) acc5[r][v]=0.f;
    }
    #pragma unroll
    for (int j=0;j<4;j++){
      const int ub = lo16*32 + j*8;
      f32x4 w0[5], w1[5];
      #pragma unroll
      for (int v=0;v<5;v++){
        const float* wp = outW + v*512 + ub;
        w0[v] = *(const f32x4*)(wp);
        w1[v] = *(const f32x4*)(wp+4);
      }
      #pragma unroll
      for (int r=0;r<4;r++){
        const unsigned short* hh = h1ih + (size_t)(r0+r)*512 + ub;
        const unsigned short* hl = h1il + (size_t)(r0+r)*512 + ub;
        bf16x8 vh = *(const bf16x8*)hh;
        bf16x8 vl = *(const bf16x8*)hl;
        #pragma unroll
        for (int m=0;m<4;m++){
          float hv = bf2f((unsigned short)vh[m]) + bf2f((unsigned short)vl[m]);
          #pragma unroll
          for (int v=0;v<5;v++) acc5[r][v] += hv * w0[v][m];
        }
        #pragma unroll
        for (int m=0;m<4;m++){
          float hv = bf2f((unsigned short)vh[m+4]) + bf2f((unsigned short)vl[m+4]);
          #pragma unroll
          for (int v=0;v<5;v++) acc5[r][v] += hv * w1[v][m];
        }
      }
    }
    #pragma unroll
    for (int r=0;r<4;r++){
      #pragma unroll
      for (int v=0;v<5;v++){
        float s = acc5[r][v];
        s += __shfl_xor(s, 1);
        s += __shfl_xor(s, 2);
        s += __shfl_xor(s, 4);
        s += __shfl_xor(s, 8);
        acc5[r][v] = s + outb[v];
      }
      float best = acc5[r][0]; int tk = 0;
      if (acc5[r][1] > best){ best = acc5[r][1]; tk = 1; }
      if (acc5[r][2] > best){ best = acc5[r][2]; tk = 2; }
      if (acc5[r][3] > best){ best = acc5[r][3]; tk = 3; }
      if (acc5[r][4] > best){ best = acc5[r][4]; tk = 4; }
      tkr[r] = tk;
    }
    if (by == 0 && wu == 0 && lo16 == 0){
      #pragma unroll
      for (int r=0;r<4;r++){
        float* op = out + ((size_t)(r0+r)*TDEC + (t-1))*5;
        #pragma unroll
        for (int v=0;v<5;v++) op[v] = acc5[r][v];
      }
    }
  }

  #pragma unroll
  for (int r=0;r<4;r++){
    const int e = r0 + r;
    const float* ep = egen0 + (size_t)tkr[r]*2048 + u;
    float zi = aHH[0][r]+aLH[0][r]+aHL[0][r] + ep[0];
    float zf = aHH[1][r]+aLH[1][r]+aHL[1][r] + ep[512];
    float zg = aHH[2][r]+aLH[2][r]+aHL[2][r] + ep[1024];
    float zo = aHH[3][r]+aLH[3][r]+aHL[3][r] + ep[1536];
    const size_t idx = (size_t)e*512 + u;
    float c = sigf(zf)*cst[idx] + sigf(zi)*tanhf(zg);
    float h = sigf(zo)*tanhf(c);
    cst[idx] = c;
    unsigned short hb = f2bf(h);
    hoh[idx] = hb;
    hol[idx] = f2bf(h - bf2f(hb));
  }
}

// ------------- decoder layer 1 (staged MFMA, pure LSTM) ---------------------
// K=1024 = [x(=h0out); h1prev], KT=32: 8 chunks of 4 ks.
__global__ void __launch_bounds__(512,1) dec_l1_mfma(
    const unsigned short* __restrict__ xh, const unsigned short* __restrict__ xl,
    const unsigned short* __restrict__ wh, const unsigned short* __restrict__ wl,
    const float* __restrict__ bias,
    const unsigned short* __restrict__ hih, const unsigned short* __restrict__ hil,
    unsigned short* __restrict__ hoh, unsigned short* __restrict__ hol,
    float* __restrict__ cst)
{
  __shared__ unsigned short bsm[2][32768];
  const int bid = blockIdx.x;
  const int by = bid & 15;
  const int bx = bid >> 4;
  const int e0 = bx * 64;
  const int lane = threadIdx.x & 63;
  const int w = threadIdx.x >> 6;
  const int wm = w & 3, wu = w >> 2;
  const int ut = by*2 + wu;
  const int lo16 = lane & 15, kgrp = lane >> 4;
  const int arow = e0 + wm*16 + lo16;
  const int u = ut*16 + lo16;
  const int r0 = e0 + wm*16 + kgrp*4;

  const unsigned short* pxh = xh  + (size_t)arow*512 + kgrp*8;
  const unsigned short* pxl = xl  + (size_t)arow*512 + kgrp*8;
  const unsigned short* pah = hih + (size_t)arow*512 + kgrp*8;
  const unsigned short* pal = hil + (size_t)arow*512 + kgrp*8;

  auto STAGE = [&](int c){
    #pragma unroll
    for (int i=0;i<8;i++){
      int id = w*8 + i;
      int hl  = id & 1;
      int q   = (id >> 1) & 3;
      int wu2 = (id >> 3) & 1;
      int ksl = id >> 4;
      int ks  = c*4 + ksl;
      const unsigned short* src = (hl ? wl : wh)
          + (((size_t)(q*32 + by*2 + wu2)*32 + ks)*64 + lane)*8;
      __builtin_amdgcn_global_load_lds((const void*)src,
          (void*)(&bsm[c & 1][id*512]), 16, 0, 0);
    }
  };

  const f32x4 z4 = {0.f,0.f,0.f,0.f};
  f32x4 aHH[4]={z4,z4,z4,z4}, aLH[4]={z4,z4,z4,z4}, aHL[4]={z4,z4,z4,z4};

  STAGE(0);
  __syncthreads();
  for (int c=0; c<8; c++){
    if (c+1 < 8) STAGE(c+1);
    const unsigned short* bb = &bsm[c&1][0];
    const unsigned short* pAh = (c < 4) ? pxh : pah;
    const unsigned short* pAl = (c < 4) ? pxl : pal;
    const int ksA = (c & 3)*4;
    #pragma unroll
    for (int ksl=0; ksl<4; ksl++){
      bf16x8 ah = *(const bf16x8*)(pAh + (size_t)(ksA+ksl)*32);
      bf16x8 al = *(const bf16x8*)(pAl + (size_t)(ksA+ksl)*32);
      #pragma unroll
      for (int q=0;q<4;q++){
        int fid = ((ksl*2 + wu)*4 + q)*2;
        bf16x8 bh = *(const bf16x8*)(bb + fid*512     + lane*8);
        bf16x8 bl = *(const bf16x8*)(bb + fid*512+512 + lane*8);
        aHH[q] = __builtin_amdgcn_mfma_f32_16x16x32_bf16(ah, bh, aHH[q], 0,0,0);
        aLH[q] = __builtin_amdgcn_mfma_f32_16x16x32_bf16(al, bh, aLH[q], 0,0,0);
        aHL[q] = __builtin_amdgcn_mfma_f32_16x16x32_bf16(ah, bl, aHL[q], 0,0,0);
      }
    }
    __syncthreads();
  }

  const float b0 = bias[u], b1 = bias[512+u], b2 = bias[1024+u], b3 = bias[1536+u];
  #pragma unroll
  for (int r=0;r<4;r++){
    const int e = r0 + r;
    float zi = aHH[0][r]+aLH[0][r]+aHL[0][r] + b0;
    float zf = aHH[1][r]+aLH[1][r]+aHL[1][r] + b1;
    float zg = aHH[2][r]+aLH[2][r]+aHL[2][r] + b2;
    float zo = aHH[3][r]+aLH[3][r]+aHL[3][r] + b3;
    const size_t idx = (size_t)e*512 + u;
    float c = sigf(zf)*cst[idx] + sigf(zi)*tanhf(zg);
    float h = sigf(zo)*tanhf(c);
    cst[idx] = c;
    unsigned short hb = f2bf(h);
    hoh[idx] = hb;
    hol[idx] = f2bf(h - bf2f(hb));
  }
}

// final-step logits (t = TDEC-1): one wave per batch elem
__global__ void dec_outF(const unsigned short* __restrict__ h1h,
                         const unsigned short* __restrict__ h1l,
                         const float* __restrict__ outW,
                         const float* __restrict__ outb,
                         float* __restrict__ out){
  const int lane = threadIdx.x & 63;
  const int e = blockIdx.x*4 + (threadIdx.x >> 6);
  const unsigned short* hh = h1h + (size_t)e*512;
  const unsigned short* hl = h1l + (size_t)e*512;
  float s0=0,s1=0,s2=0,s3=0,s4=0;
  for (int k=lane;k<512;k+=64){
    float hv = bf2f(hh[k]) + bf2f(hl[k]);
    s0 += hv*outW[k];
    s1 += hv*outW[512+k];
    s2 += hv*outW[1024+k];
    s3 += hv*outW[1536+k];
    s4 += hv*outW[2048+k];
  }
  #pragma unroll
  for (int off=32; off>0; off>>=1){
    s0 += __shfl_down(s0, off);
    s1 += __shfl_down(s1, off);
    s2 += __shfl_down(s2, off);
    s3 += __shfl_down(s3, off);
    s4 += __shfl_down(s4, off);
  }
  if (lane==0){
    float* op = out + ((size_t)e*TDEC + (TDEC-1))*5;
    op[0]=s0+outb[0]; op[1]=s1+outb[1]; op[2]=s2+outb[2];
    op[3]=s3+outb[3]; op[4]=s4+outb[4];
  }
}

extern "C" void kernel_launch(void* const* d_in, const int* in_sizes, int n_in,
                              void* d_out, int out_size, void* d_ws, size_t ws_size,
                              hipStream_t stream){
  (void)in_sizes; (void)n_in; (void)out_size;
  const int*   leftc    = (const int*)d_in[0];
  const int*   rightc   = (const int*)d_in[1];
  const float* emb      = (const float*)d_in[3];
  const float* ctx0_Wih = (const float*)d_in[4];
  const float* ctx0_Whh = (const float*)d_in[5];
  const float* ctx0_b   = (const float*)d_in[6];
  const float* ctx1_Wih = (const float*)d_in[7];
  const float* ctx1_Whh = (const float*)d_in[8];
  const float* ctx1_b   = (const float*)d_in[9];
  const float* gen0_Wih = (const float*)d_in[10];
  const float* gen0_Whh = (const float*)d_in[11];
  const float* gen0_b   = (const float*)d_in[12];
  const float* gen1_Wih = (const float*)d_in[13];
  const float* gen1_Whh = (const float*)d_in[14];
  const float* gen1_b   = (const float*)d_in[15];
  const float* out_W    = (const float*)d_in[16];
  const float* out_b    = (const float*)d_in[17];
  float* out = (float*)d_out;

  char* p = (char*)d_ws;
  auto carve = [&](size_t nfloats)->float*{
    float* r = (float*)p;
    p += ((nfloats*sizeof(float) + 255) & ~(size_t)255);
    return r;
  };
  auto carveu = [&](size_t nush)->unsigned short*{
    return (unsigned short*)carve((nush + 1)/2);
  };
  float* ectx0  = carve(2*5*1024);
  float* egen0  = carve(5*2048);
  float* leftF  = carve((size_t)BATCH*HG);
  float* rightF = carve((size_t)BATCH*HG);
  float* c0s    = carve((size_t)BATCH*HG);
  float* c1s    = carve((size_t)BATCH*HG);
  unsigned short* c0pkh = carveu((size_t)2*1024*256);
  unsigned short* c0pkl = carveu((size_t)2*1024*256);
  unsigned short* c1pkh = carveu((size_t)2*1024*768);
  unsigned short* c1pkl = carveu((size_t)2*1024*768);
  unsigned short* pk0h = carveu((size_t)2048*512);
  unsigned short* pk0l = carveu((size_t)2048*512);
  unsigned short* pk1h = carveu((size_t)2048*1024);
  unsigned short* pk1l = carveu((size_t)2048*1024);
  unsigned short* h0ha = carveu((size_t)BATCH*HG);
  unsigned short* h0la = carveu((size_t)BATCH*HG);
  unsigned short* h0hb = carveu((size_t)BATCH*HG);
  unsigned short* h0lb = carveu((size_t)BATCH*HG);
  unsigned short* h1ha = carveu((size_t)BATCH*HG);
  unsigned short* h1la = carveu((size_t)BATCH*HG);
  unsigned short* h1hb = carveu((size_t)BATCH*HG);
  unsigned short* h1lb = carveu((size_t)BATCH*HG);
  unsigned short* y0h = carveu((size_t)L_SEQ*BATCH*512);   // 105 MB
  unsigned short* y0l = carveu((size_t)L_SEQ*BATCH*512);   // 105 MB
  if ((size_t)(p - (char*)d_ws) > ws_size) return;  // insufficient workspace -> loud fail

  // weight packs (fragment-linear bf16 hi/lo)
  for (int d=0; d<2; d++){
    pack_w<<<128, 256, 0, stream>>>(ctx0_Whh + (size_t)d*1024*256, 1024, 256, 8, 0,
                                    c0pkh + (size_t)d*262144, c0pkl + (size_t)d*262144);
    pack_w<<<256, 256, 0, stream>>>(ctx1_Wih + (size_t)d*1024*512, 1024, 512, 24, 0,
                                    c1pkh + (size_t)d*786432, c1pkl + (size_t)d*786432);
    pack_w<<<128, 256, 0, stream>>>(ctx1_Whh + (size_t)d*1024*256, 1024, 256, 24, 16,
                                    c1pkh + (size_t)d*786432, c1pkl + (size_t)d*786432);
  }
  pack_w<<<512, 256, 0, stream>>>(gen0_Whh, 2048, 512, 16,  0, pk0h, pk0l);
  pack_w<<<512, 256, 0, stream>>>(gen1_Wih, 2048, 512, 32,  0, pk1h, pk1l);
  pack_w<<<512, 256, 0, stream>>>(gen1_Whh, 2048, 512, 32, 16, pk1h, pk1l);

  embprep<<<(20480+255)/256, 256, 0, stream>>>(emb, ctx0_Wih, ctx0_b,
                                               gen0_Wih, gen0_b, ectx0, egen0);

  // left encode (finals at t=99), then right (finals at t=0); y0 reused
  ctx_l0_mfma<<<128, 512, 0, stream>>>(leftc, ectx0, c0pkh, c0pkl, y0h, y0l);
  ctx_l1_mfma<<<128, 512, 0, stream>>>(y0h, y0l, c1pkh, c1pkl, ctx1_b, leftF, L_SEQ-1);
  ctx_l0_mfma<<<128, 512, 0, stream>>>(rightc, ectx0, c0pkh, c0pkl, y0h, y0l);
  ctx_l1_mfma<<<128, 512, 0, stream>>>(y0h, y0l, c1pkh, c1pkl, ctx1_b, rightF, 0);

  combine_init2<<<(BATCH*HG+255)/256, 256, 0, stream>>>(leftF, rightF,
                                                        h0ha, h0la, h1ha, h1la,
                                                        c0s, c1s);

  for (int t=0;t<TDEC;t++){
    unsigned short* h0ih = (t&1)? h0hb : h0ha;
    unsigned short* h0il = (t&1)? h0lb : h0la;
    unsigned short* h0oh = (t&1)? h0ha : h0hb;
    unsigned short* h0ol = (t&1)? h0la : h0lb;
    unsigned short* h1ih = (t&1)? h1hb : h1ha;
    unsigned short* h1il = (t&1)? h1lb : h1la;
    unsigned short* h1oh = (t&1)? h1ha : h1hb;
    unsigned short* h1ol = (t&1)? h1la : h1lb;
    dec_l0_mfma<<<256, 512, 0, stream>>>(egen0, pk0h, pk0l,
                                         h0ih, h0il, h1ih, h1il,
                                         h0oh, h0ol, c0s,
                                         out_W, out_b, out, t);
    dec_l1_mfma<<<256, 512, 0, stream>>>(h0oh, h0ol, pk1h, pk1l, gen1_b,
                                         h1ih, h1il, h1oh, h1ol, c1s);
  }
  // t = TDEC-1 logits (h1 final lives in the 'a' buffers after odd t=255)
  dec_outF<<<256, 256, 0, stream>>>(h1ha, h1la, out_W, out_b, out);
}